// Round 8
// baseline (738.784 us; speedup 1.0000x reference)
//
#include <hip/hip_runtime.h>
#include <math.h>

// Problem constants
#define BB 4
#define CC 64
#define C2 128
#define HH 128
#define WW 256
#define NN (BB*HH)          // 512 row-pairs
#define EPSBN 1e-5f

typedef _Float16 f16;
typedef _Float16 half8 __attribute__((ext_vector_type(8)));
typedef float f32x4 __attribute__((ext_vector_type(4)));

// ---------------------------------------------------------------------------
// K0: weight prep — rb_w fp32 [o][icg][3][3] -> f16 [g][mo][ks*32+ic]
// ---------------------------------------------------------------------------
__global__ __launch_bounds__(256) void k_wprep(
    const float* __restrict__ w1, const float* __restrict__ w2,
    f16* __restrict__ wp1, f16* __restrict__ wp2)
{
    int g = blockIdx.x; int which = blockIdx.y;
    const float* src = which ? w2 : w1;
    f16* dst = which ? wp2 : wp1;
    for (int p = threadIdx.x; p < 9216; p += 256) {
        int mo = p / 288; int kr = p - mo*288;
        int ks = kr >> 5; int ic = kr & 31;
        dst[g*9216 + p] = (f16)src[((g*32 + mo)*32 + ic)*9 + ks];
    }
}

// ---------------------------------------------------------------------------
// K1: fused 1x1 conv (64->64) + concat + batchnorm -> u (channel-last f16)
// ---------------------------------------------------------------------------
__global__ __launch_bounds__(256) void k_catbn_m(
    const float* __restrict__ x, const float* __restrict__ cw, const float* __restrict__ cb,
    const float* __restrict__ g, const float* __restrict__ bb_, const float* __restrict__ m,
    const float* __restrict__ v, f16* __restrict__ u)
{
    __shared__ f16 Xl[256][72];   // [px][ic]
    __shared__ f16 Wl[64][72];    // [oc][ic]
    __shared__ float sS[64], sT[64], sS2[64], sT2[64];
    int n = blockIdx.x; int b = n >> 7; int h = n & 127; int t = threadIdx.x;
    for (int p = t; p < 2048; p += 256) {
        int idx = p * 2; int o = idx >> 6, i = idx & 63;
        union { f16 h[2]; unsigned int u1; } pr;
        pr.h[0] = (f16)cw[idx]; pr.h[1] = (f16)cw[idx + 1];
        *(unsigned int*)&Wl[o][i] = pr.u1;
    }
    if (t < 64) {
        float inv = rsqrtf(v[t] + EPSBN); float s = g[t] * inv;
        sS[t] = s; sT[t] = bb_[t] + s * (cb[t] - m[t]);
        float inv2 = rsqrtf(v[t + 64] + EPSBN); float s2 = g[t + 64] * inv2;
        sS2[t] = s2; sT2[t] = bb_[t + 64] - s2 * m[t + 64];
    }
    __syncthreads();
    f16* up = u + ((size_t)(n*256 + t)) * 128;
    for (int c8 = 0; c8 < 8; ++c8) {
        float xv8[8];
#pragma unroll
        for (int j = 0; j < 8; ++j)
            xv8[j] = x[(((b*64 + c8*8 + j)*128 + h) << 8) + t];
        union { f16 h[8]; uint4 v4; } pk;
#pragma unroll
        for (int j = 0; j < 8; ++j) {
            int c = c8*8 + j;
            pk.h[j] = (f16)(sS2[c]*xv8[j] + sT2[c]);
        }
        *(uint4*)(up + 64 + c8*8) = pk.v4;
#pragma unroll
        for (int j2 = 0; j2 < 4; ++j2) {
            union { f16 h[2]; unsigned int u1; } q;
            q.h[0] = (f16)xv8[j2*2]; q.h[1] = (f16)xv8[j2*2 + 1];
            *(unsigned int*)&Xl[t][c8*8 + j2*2] = q.u1;
        }
    }
    __syncthreads();
    int lane = t & 63, wv = t >> 6;
    int m16 = lane & 15, quad = lane >> 4;
    half8 af[4][2], bf[4][2];
#pragma unroll
    for (int mt = 0; mt < 4; ++mt)
#pragma unroll
        for (int kk = 0; kk < 2; ++kk)
            af[mt][kk] = *(const half8*)&Wl[mt*16 + m16][kk*32 + quad*8];
#pragma unroll
    for (int nt = 0; nt < 4; ++nt)
#pragma unroll
        for (int kk = 0; kk < 2; ++kk)
            bf[nt][kk] = *(const half8*)&Xl[wv*64 + nt*16 + m16][kk*32 + quad*8];
    f32x4 acc[4][4] = {};
#pragma unroll
    for (int mt = 0; mt < 4; ++mt)
#pragma unroll
        for (int nt = 0; nt < 4; ++nt) {
            acc[mt][nt] = __builtin_amdgcn_mfma_f32_16x16x32_f16(af[mt][0], bf[nt][0], acc[mt][nt], 0, 0, 0);
            acc[mt][nt] = __builtin_amdgcn_mfma_f32_16x16x32_f16(af[mt][1], bf[nt][1], acc[mt][nt], 0, 0, 0);
        }
#pragma unroll
    for (int mt = 0; mt < 4; ++mt) {
        int ocb = mt*16 + quad*4;
        float s4[4], t4[4];
        *(float4*)s4 = *(const float4*)&sS[ocb];
        *(float4*)t4 = *(const float4*)&sT[ocb];
#pragma unroll
        for (int nt = 0; nt < 4; ++nt) {
            int px = wv*64 + nt*16 + m16;
            union { f16 h[4]; uint2 u2; } ov;
#pragma unroll
            for (int r = 0; r < 4; ++r)
                ov.h[r] = (f16)(s4[r]*acc[mt][nt][r] + t4[r]);
            *(uint2*)(u + ((size_t)(n*256 + px))*128 + ocb) = ov.u2;
        }
    }
}

// ---------------------------------------------------------------------------
// K2/K3: grouped 3x3 conv, implicit-GEMM f16 MFMA.
// 2 output rows per block (4 staged rows, 41.6 KB LDS) -> 3 blocks/CU.
// ---------------------------------------------------------------------------
template<bool LEAKY, bool RES>
__global__ __launch_bounds__(256, 3) void k_conv3r(
    const f16* __restrict__ in, const f16* __restrict__ wp,
    const float* __restrict__ bias, const f16* __restrict__ res,
    f16* __restrict__ out)
{
    __shared__ f16 Xl[4*130*40];  // [row][px][ic] px-stride 40
    int b = blockIdx.x >> 6; int h0 = (blockIdx.x & 63) * 2;
    int g = blockIdx.y; int w0 = blockIdx.z * 128;
    int t = threadIdx.x;
    int lane = t & 63, wv = t >> 6;
    int m16 = lane & 15, quad = lane >> 4;
    const f16* wg = wp + g*9216;
    half8 af[2][9];
#pragma unroll
    for (int mt = 0; mt < 2; ++mt)
#pragma unroll
        for (int ks = 0; ks < 9; ++ks)
            af[mt][ks] = *(const half8*)(wg + (mt*16 + m16)*288 + ks*32 + quad*8);
    float bo[2][4];
#pragma unroll
    for (int mt = 0; mt < 2; ++mt)
#pragma unroll
        for (int r = 0; r < 4; ++r)
            bo[mt][r] = bias[g*32 + mt*16 + quad*4 + r];
    // ---- stage 4 input rows (h0-1 .. h0+2) ----
    for (int idx = t; idx < 2080; idx += 256) {
        int r = idx / 520; int rem = idx - r*520; int p = rem >> 2; int q = rem & 3;
        int hr = h0 + r - 1; int wg2 = w0 + p - 1;
        uint4 val = make_uint4(0,0,0,0);
        if ((unsigned)wg2 < 256u && (unsigned)hr < 128u)
            val = *(const uint4*)(in + ((size_t)((b*128 + hr)*256 + wg2))*128 + g*32 + q*8);
        *(uint4*)&Xl[(r*130 + p)*40 + q*8] = val;
    }
    __syncthreads();
    int px0 = wv*32 + m16;
#pragma unroll
    for (int rr = 0; rr < 2; ++rr) {
        f32x4 acc[2][2] = {};
#pragma unroll
        for (int ks = 0; ks < 9; ++ks) {
            int ky = ks / 3, kx = ks - ky*3;
            half8 bf0 = *(const half8*)&Xl[((rr + ky)*130 + px0 + kx)*40 + quad*8];
            half8 bf1 = *(const half8*)&Xl[((rr + ky)*130 + px0 + 16 + kx)*40 + quad*8];
            acc[0][0] = __builtin_amdgcn_mfma_f32_16x16x32_f16(af[0][ks], bf0, acc[0][0], 0, 0, 0);
            acc[0][1] = __builtin_amdgcn_mfma_f32_16x16x32_f16(af[0][ks], bf1, acc[0][1], 0, 0, 0);
            acc[1][0] = __builtin_amdgcn_mfma_f32_16x16x32_f16(af[1][ks], bf0, acc[1][0], 0, 0, 0);
            acc[1][1] = __builtin_amdgcn_mfma_f32_16x16x32_f16(af[1][ks], bf1, acc[1][1], 0, 0, 0);
        }
        int h = h0 + rr;
#pragma unroll
        for (int mt = 0; mt < 2; ++mt)
#pragma unroll
            for (int nt = 0; nt < 2; ++nt) {
                int px = w0 + wv*32 + nt*16 + m16;
                int oc = g*32 + mt*16 + quad*4;
                size_t off = ((size_t)((b*128 + h)*256 + px))*128 + oc;
                float rv4[4] = {0.f, 0.f, 0.f, 0.f};
                if (RES) {
                    union { f16 h[4]; uint2 v2; } rrd;
                    rrd.v2 = *(const uint2*)(res + off);
#pragma unroll
                    for (int r = 0; r < 4; ++r) rv4[r] = (float)rrd.h[r];
                }
                union { f16 h[4]; uint2 v2; } ov;
#pragma unroll
                for (int r = 0; r < 4; ++r) {
                    float y = acc[mt][nt][r] + bo[mt][r];
                    if (LEAKY) y = y > 0.f ? y : 0.1f*y;
                    if (RES) y += rv4[r];
                    ov.h[r] = (f16)y;
                }
                *(uint2*)(out + off) = ov.v2;
            }
    }
}

// ---------------------------------------------------------------------------
// K4: grouped 1x1 conv (128->64, groups=2) + row-mean subtraction, MFMA f16.
// ---------------------------------------------------------------------------
__global__ __launch_bounds__(256, 2) void k_conv1x1m(
    const f16* __restrict__ in, const float* __restrict__ wgt,
    f16* __restrict__ outq)
{
    __shared__ f16 Xl[256][72];       // one group's 64 ic (+8 pad)
    __shared__ f16 Wl[64][72];        // all 64 oc, within-group ic
    __shared__ float partial[4][64];  // per-wave px-sums per oc
    __shared__ float meanS[64];
    int n = blockIdx.x; int t = threadIdx.x;
    int lane = t & 63, wv = t >> 6;
    int m16 = lane & 15, quad = lane >> 4;
    for (int p = t; p < 2048; p += 256) {
        int idx = p * 2; int o = idx >> 6, i = idx & 63;
        union { f16 h[2]; unsigned int u1; } pr;
        pr.h[0] = (f16)wgt[idx]; pr.h[1] = (f16)wgt[idx + 1];
        *(unsigned int*)&Wl[o][i] = pr.u1;
    }
    f32x4 acc[4][4] = {};             // [oc tile 0..3][px tile 0..3]
    const f16* rp = in + ((size_t)n*256 + t)*128;
    for (int g = 0; g < 2; ++g) {
#pragma unroll
        for (int i8 = 0; i8 < 8; ++i8)
            *(uint4*)&Xl[t][i8*8] = *(const uint4*)(rp + g*64 + i8*8);
        __syncthreads();
        half8 af[2][2], bf[4][2];
#pragma unroll
        for (int ml = 0; ml < 2; ++ml)
#pragma unroll
            for (int kk = 0; kk < 2; ++kk)
                af[ml][kk] = *(const half8*)&Wl[g*32 + ml*16 + m16][kk*32 + quad*8];
#pragma unroll
        for (int nt = 0; nt < 4; ++nt)
#pragma unroll
            for (int kk = 0; kk < 2; ++kk)
                bf[nt][kk] = *(const half8*)&Xl[wv*64 + nt*16 + m16][kk*32 + quad*8];
#pragma unroll
        for (int ml = 0; ml < 2; ++ml)
#pragma unroll
            for (int nt = 0; nt < 4; ++nt) {
                int mt = g*2 + ml;
                acc[mt][nt] = __builtin_amdgcn_mfma_f32_16x16x32_f16(af[ml][0], bf[nt][0], acc[mt][nt], 0, 0, 0);
                acc[mt][nt] = __builtin_amdgcn_mfma_f32_16x16x32_f16(af[ml][1], bf[nt][1], acc[mt][nt], 0, 0, 0);
            }
        __syncthreads();
    }
#pragma unroll
    for (int mt = 0; mt < 4; ++mt)
#pragma unroll
        for (int r = 0; r < 4; ++r) {
            float s = acc[mt][0][r] + acc[mt][1][r] + acc[mt][2][r] + acc[mt][3][r];
            s += __shfl_xor(s, 1); s += __shfl_xor(s, 2);
            s += __shfl_xor(s, 4); s += __shfl_xor(s, 8);
            if (m16 == 0) partial[wv][mt*16 + quad*4 + r] = s;
        }
    __syncthreads();
    if (t < 64)
        meanS[t] = (partial[0][t] + partial[1][t] + partial[2][t] + partial[3][t]) * (1.0f/256.0f);
    __syncthreads();
    f16* qp = outq + ((size_t)n*256)*64;
#pragma unroll
    for (int mt = 0; mt < 4; ++mt) {
        int ocb = mt*16 + quad*4;
        float m4[4]; *(float4*)m4 = *(const float4*)&meanS[ocb];
#pragma unroll
        for (int nt = 0; nt < 4; ++nt) {
            int px = wv*64 + nt*16 + m16;
            union { f16 h[4]; uint2 u2; } ov;
#pragma unroll
            for (int r = 0; r < 4; ++r)
                ov.h[r] = (f16)(acc[mt][nt][r] - m4[r]);
            *(uint2*)(qp + (size_t)px*64 + ocb) = ov.u2;
        }
    }
}

// ---------------------------------------------------------------------------
// K5: fused attention, no S-buffer, ONE direction per block.
// grid (512, 2): blockIdx.y = 0 -> left output, 1 -> right (S^T recompute).
// Each block: phase-1 stats (row+col, shfl-fused) + ONE chunked pass.
// LDS 30 KB, VGPR<=64 (__launch_bounds__(512,8)) -> 4 blocks/CU ->
// all 1024 blocks resident in a single round; per-block critical path
// is half of R7's serial two-pass version.
// ---------------------------------------------------------------------------
__device__ __forceinline__ void attn_pass3(
    const f16* __restrict__ Ap, const f16* __restrict__ Bp, char* pool,
    const float* __restrict__ myM, const float* __restrict__ myI,  // by row r
    const float* __restrict__ oM,  const float* __restrict__ oI,   // by col j
    const float* __restrict__ xB, const float* __restrict__ xP,
    float* __restrict__ outp, int b, int h, int t)
{
    f16 (*Pl)[40] = (f16(*)[40])pool;               // rows +2 (window pad)
    f16 (*Xl)[40] = (f16(*)[40])(pool + 20800);
    float* scr = (float*)(pool + 20800);            // overlays Xl (post-loop)
    float* Vv  = (float*)(pool + 22848);
    int lane = t & 63, wv = t >> 6;
    int m16 = lane & 15, quad = lane >> 4;
    int W = wv * 32;
    int r = t & 255, hc = t >> 8;
    int cbase = hc * 16;
    float rm = myM[r], ri = myI[r];
    int xc = t >> 3, xj = (t & 7) * 4;
    const float* xg = xB + ((size_t)(b*64 + xc)*128 + h)*256;
    // A fragments for this wave's 32 rows (constant across chunks)
    half8 af[2][2];
#pragma unroll
    for (int mt = 0; mt < 2; ++mt)
#pragma unroll
        for (int kk = 0; kk < 2; ++kk)
            af[mt][kk] = *(const half8*)(Ap + (size_t)(W + mt*16 + m16)*64 + kk*32 + quad*8);
    f32x4 acc[2][4] = {};
    float vacc = 0.f;
    for (int kc = 0; kc < 256; kc += 32) {
        // ---- recompute S slab (32 rows/wave x 32 chunk cols) ----
        half8 bf[2][2];
#pragma unroll
        for (int nt = 0; nt < 2; ++nt)
#pragma unroll
            for (int kk = 0; kk < 2; ++kk)
                bf[nt][kk] = *(const half8*)(Bp + (size_t)(kc + nt*16 + m16)*64 + kk*32 + quad*8);
        f32x4 s1[2][2] = {};
#pragma unroll
        for (int mt = 0; mt < 2; ++mt)
#pragma unroll
            for (int nt = 0; nt < 2; ++nt) {
                s1[mt][nt] = __builtin_amdgcn_mfma_f32_16x16x32_f16(af[mt][0], bf[nt][0], s1[mt][nt], 0, 0, 0);
                s1[mt][nt] = __builtin_amdgcn_mfma_f32_16x16x32_f16(af[mt][1], bf[nt][1], s1[mt][nt], 0, 0, 0);
            }
        // stage Xl chunk
        {
            float4 x4 = *(const float4*)(xg + kc + xj);
            union { f16 h[4]; uint2 v2; } px;
            px.h[0] = (f16)x4.x; px.h[1] = (f16)x4.y;
            px.h[2] = (f16)x4.z; px.h[3] = (f16)x4.w;
            *(uint2*)&Xl[xc][xj] = px.v2;
        }
        // scatter raw S (C-layout) into Pl
#pragma unroll
        for (int mt = 0; mt < 2; ++mt)
#pragma unroll
            for (int nt = 0; nt < 2; ++nt)
#pragma unroll
                for (int rr = 0; rr < 4; ++rr)
                    Pl[W + mt*16 + quad*4 + rr + 2][nt*16 + m16] = (f16)s1[mt][nt][rr];
        __syncthreads();
        // ---- row pass: raw -> P (in place), keep raw in regs for Bv ----
        float sraw[16];
        char* pb = (char*)&Pl[r + 2][cbase];
        {
            half8 v0 = *(const half8*)pb;
            half8 v1 = *(const half8*)(pb + 16);
            half8 p0, p1;
#pragma unroll
            for (int e = 0; e < 8; ++e) {
                sraw[e] = (float)v0[e];
                p0[e] = (f16)(__expf(sraw[e] - rm) * ri);
            }
#pragma unroll
            for (int e = 0; e < 8; ++e) {
                sraw[8 + e] = (float)v1[e];
                p1[e] = (f16)(__expf(sraw[8 + e] - rm) * ri);
            }
            *(half8*)pb = p0; *(half8*)(pb + 16) = p1;
        }
        __syncthreads();
        // ---- window + V partial ----
#pragma unroll
        for (int j8 = 0; j8 < 2; ++j8) {
            const char* wb = (const char*)&Pl[r][cbase + j8*8];
            half8 w0 = *(const half8*)(wb);
            half8 w1 = *(const half8*)(wb + 80);
            half8 w2 = *(const half8*)(wb + 160);
            half8 w3 = *(const half8*)(wb + 240);
            half8 w4 = *(const half8*)(wb + 320);
            half8 win = w0 + w1 + w2 + w3 + w4;
#pragma unroll
            for (int e = 0; e < 8; ++e) {
                int j = kc + cbase + j8*8 + e;
                float Bv = __expf(sraw[j8*8 + e] - oM[j]) * oI[j];
                vacc = fmaf((float)win[e], Bv, vacc);
            }
        }
        // ---- PV MFMA ----
        half8 pa[2], xb_[4];
#pragma unroll
        for (int mt = 0; mt < 2; ++mt)
            pa[mt] = *(const half8*)((const char*)&Pl[W + mt*16 + m16 + 2][0] + quad*16);
#pragma unroll
        for (int nt = 0; nt < 4; ++nt)
            xb_[nt] = *(const half8*)((const char*)&Xl[nt*16 + m16][0] + quad*16);
#pragma unroll
        for (int mt = 0; mt < 2; ++mt)
#pragma unroll
            for (int nt = 0; nt < 4; ++nt)
                acc[mt][nt] = __builtin_amdgcn_mfma_f32_16x16x32_f16(pa[mt], xb_[nt], acc[mt][nt], 0, 0, 0);
        __syncthreads();
    }
    // ---- V merge + epilogue ----
    scr[hc*256 + r] = vacc;
    __syncthreads();
    if (t < 256) Vv[t] = scr[t] + scr[256 + t];
    __syncthreads();
#pragma unroll
    for (int mt = 0; mt < 2; ++mt) {
        int i0 = W + mt*16 + quad*4;
        float v4[4];
        *(float4*)v4 = *(const float4*)&Vv[i0];
        float tv[4];
#pragma unroll
        for (int rr = 0; rr < 4; ++rr) tv[rr] = tanhf(5.f*v4[rr]);
#pragma unroll
        for (int nt = 0; nt < 4; ++nt) {
            int c = nt*16 + m16;
            size_t base = (((size_t)(b*64 + c)*128 + h) << 8) + i0;
            float xp4[4]; *(float4*)xp4 = *(const float4*)&xP[base];
            float o4[4];
#pragma unroll
            for (int rr = 0; rr < 4; ++rr)
                o4[rr] = xp4[rr]*(1.f - tv[rr]) + acc[mt][nt][rr]*tv[rr];
            *(float4*)&outp[base] = *(float4*)o4;
        }
    }
}

__global__ __launch_bounds__(512, 8) void k_attn4(
    const f16* __restrict__ Q, const f16* __restrict__ K,
    const float* __restrict__ xl, const float* __restrict__ xr,
    float* __restrict__ outL, float* __restrict__ outR)
{
    __shared__ __align__(16) char pool[25920];  // Pl/Xl ∪ colM/colS ∪ scr/Vv
    __shared__ float rmS[256], riS[256], cmS[256], ciS[256];
    float* colM = (float*)pool;            // [8][256] per-wave col partial max
    float* colS = (float*)(pool + 8192);   // [8][256] per-wave col partial sum
    int n = blockIdx.x; int b = n >> 7; int h = n & 127;
    int pass = blockIdx.y;
    int t = threadIdx.x;
    int lane = t & 63, wv = t >> 6;
    int m16 = lane & 15, quad = lane >> 4;
    int W = wv * 32;

    // ---- phase 1: S = Q·K^T, stats only (no store) ----
    const f16* ag = Q + (size_t)n*16384;
    const f16* bg = K + (size_t)n*16384;
    half8 af1[2][2];
#pragma unroll
    for (int mt = 0; mt < 2; ++mt)
#pragma unroll
        for (int kk = 0; kk < 2; ++kk)
            af1[mt][kk] = *(const half8*)(ag + (size_t)(W + mt*16 + m16)*64 + kk*32 + quad*8);
    float rowm[8], rows_[8];
#pragma unroll
    for (int i = 0; i < 8; ++i) { rowm[i] = -1e30f; rows_[i] = 0.f; }
    for (int jc = 0; jc < 256; jc += 64) {
        half8 bf1[4][2];
#pragma unroll
        for (int nt = 0; nt < 4; ++nt)
#pragma unroll
            for (int kk = 0; kk < 2; ++kk)
                bf1[nt][kk] = *(const half8*)(bg + (size_t)(jc + nt*16 + m16)*64 + kk*32 + quad*8);
        f32x4 acc1[2][4] = {};
#pragma unroll
        for (int mt = 0; mt < 2; ++mt)
#pragma unroll
            for (int nt = 0; nt < 4; ++nt) {
                acc1[mt][nt] = __builtin_amdgcn_mfma_f32_16x16x32_f16(af1[mt][0], bf1[nt][0], acc1[mt][nt], 0, 0, 0);
                acc1[mt][nt] = __builtin_amdgcn_mfma_f32_16x16x32_f16(af1[mt][1], bf1[nt][1], acc1[mt][nt], 0, 0, 0);
            }
        // round to f16 so stats match the recomputed (rounded) S exactly
#pragma unroll
        for (int mt = 0; mt < 2; ++mt)
#pragma unroll
            for (int nt = 0; nt < 4; ++nt)
#pragma unroll
                for (int r = 0; r < 4; ++r)
                    acc1[mt][nt][r] = (float)(f16)acc1[mt][nt][r];
        // row stats: reduce over 4 in-lane cols + 16 m16-lanes, online across jc
#pragma unroll
        for (int mt = 0; mt < 2; ++mt)
#pragma unroll
            for (int r = 0; r < 4; ++r) {
                float lm = fmaxf(fmaxf(acc1[mt][0][r], acc1[mt][1][r]),
                                 fmaxf(acc1[mt][2][r], acc1[mt][3][r]));
                lm = fmaxf(lm, __shfl_xor(lm, 1));
                lm = fmaxf(lm, __shfl_xor(lm, 2));
                lm = fmaxf(lm, __shfl_xor(lm, 4));
                lm = fmaxf(lm, __shfl_xor(lm, 8));
                float le = __expf(acc1[mt][0][r] - lm) + __expf(acc1[mt][1][r] - lm)
                         + __expf(acc1[mt][2][r] - lm) + __expf(acc1[mt][3][r] - lm);
                le += __shfl_xor(le, 1); le += __shfl_xor(le, 2);
                le += __shfl_xor(le, 4); le += __shfl_xor(le, 8);
                int idx = mt*4 + r;
                float nm = fmaxf(rowm[idx], lm);
                rows_[idx] = rows_[idx]*__expf(rowm[idx] - nm) + le*__expf(lm - nm);
                rowm[idx] = nm;
            }
        // col stats: reduce over 8 in-lane rows + 4 quads -> per-wave partial
#pragma unroll
        for (int nt = 0; nt < 4; ++nt) {
            float lm = acc1[0][nt][0];
#pragma unroll
            for (int r = 1; r < 4; ++r) lm = fmaxf(lm, acc1[0][nt][r]);
#pragma unroll
            for (int r = 0; r < 4; ++r) lm = fmaxf(lm, acc1[1][nt][r]);
            lm = fmaxf(lm, __shfl_xor(lm, 16));
            lm = fmaxf(lm, __shfl_xor(lm, 32));
            float le = 0.f;
#pragma unroll
            for (int mt2 = 0; mt2 < 2; ++mt2)
#pragma unroll
                for (int r = 0; r < 4; ++r) le += __expf(acc1[mt2][nt][r] - lm);
            le += __shfl_xor(le, 16); le += __shfl_xor(le, 32);
            if (quad == 0) {
                int col = jc + nt*16 + m16;
                colM[wv*256 + col] = lm;
                colS[wv*256 + col] = le;
            }
        }
    }
    if (m16 == 0) {
#pragma unroll
        for (int mt = 0; mt < 2; ++mt)
#pragma unroll
            for (int r = 0; r < 4; ++r) {
                int row = W + mt*16 + quad*4 + r;
                rmS[row] = rowm[mt*4 + r];
                riS[row] = 1.0f / rows_[mt*4 + r];
            }
    }
    __syncthreads();
    // merge 8 per-wave col partials
    if (t < 256) {
        float m = colM[t], s = colS[t];
#pragma unroll
        for (int w = 1; w < 8; ++w) {
            float m2 = colM[w*256 + t], s2 = colS[w*256 + t];
            float nm = fmaxf(m, m2);
            s = s*__expf(m - nm) + s2*__expf(m2 - nm);
            m = nm;
        }
        cmS[t] = m; ciS[t] = 1.0f / s;
    }
    __syncthreads();
    // zero Pl window-pad rows (0,1 and 258,259) — pool now free
    if (t < 10)       *(uint4*)(pool + t*16)              = make_uint4(0,0,0,0);
    else if (t < 20)  *(uint4*)(pool + 20640 + (t-10)*16) = make_uint4(0,0,0,0);

    // ---- one direction per block (operands picked by pass) ----
    const f16*  Ap = pass ? bg : ag;
    const f16*  Bp = pass ? ag : bg;
    const float* mM = pass ? cmS : rmS;
    const float* mI = pass ? ciS : riS;
    const float* oM = pass ? rmS : cmS;
    const float* oI = pass ? riS : ciS;
    const float* xB = pass ? xl : xr;
    const float* xP = pass ? xr : xl;
    float* outp     = pass ? outR : outL;
    attn_pass3(Ap, Bp, pool, mM, mI, oM, oI, xB, xP, outp, b, h, t);
}

// ---------------------------------------------------------------------------
extern "C" void kernel_launch(void* const* d_in, const int* in_sizes, int n_in,
                              void* d_out, int out_size, void* d_ws, size_t ws_size,
                              hipStream_t stream)
{
    const float* x_left  = (const float*)d_in[0];
    const float* x_right = (const float*)d_in[1];
    const float* conv1_w = (const float*)d_in[2];
    const float* conv1_b = (const float*)d_in[3];
    const float* conv2_w = (const float*)d_in[4];
    const float* conv2_b = (const float*)d_in[5];
    const float* bn_g    = (const float*)d_in[6];
    const float* bn_b    = (const float*)d_in[7];
    const float* bn_m    = (const float*)d_in[8];
    const float* bn_v    = (const float*)d_in[9];
    const float* rb_w1   = (const float*)d_in[10];
    const float* rb_b1   = (const float*)d_in[11];
    const float* rb_w2   = (const float*)d_in[12];
    const float* rb_b2   = (const float*)d_in[13];
    const float* bq_w    = (const float*)d_in[14];
    const float* bs_w    = (const float*)d_in[16];

    f16* W16 = (f16*)d_ws;
    f16* u  = W16;                       // 16,777,216 els
    f16* y1 = W16 + 16777216;            // 16,777,216
    f16* r  = W16 + 33554432;            // 16,777,216
    f16* Qh = W16 + 67108864;            //  8,388,608
    f16* Kh = W16 + 75497472;            //  8,388,608
    f16* Wp1 = W16 + 84934656;           // 36,864 els (prepped rb_w1)
    f16* Wp2 = W16 + 84971520;           // 36,864 els (prepped rb_w2)

    float* out_left  = (float*)d_out;
    float* out_right = (float*)d_out + 8388608;

    // ---- weight prep (once per launch) ----
    k_wprep<<<dim3(4, 2), 256, 0, stream>>>(rb_w1, rb_w2, Wp1, Wp2);

    // ---- left branch -> Q ----
    k_catbn_m<<<NN, 256, 0, stream>>>(x_left, conv1_w, conv1_b, bn_g, bn_b, bn_m, bn_v, u);
    k_conv3r<true,  false><<<dim3(256, 4, 2), 256, 0, stream>>>(u, Wp1, rb_b1, nullptr, y1);
    k_conv3r<false, true ><<<dim3(256, 4, 2), 256, 0, stream>>>(y1, Wp2, rb_b2, u, r);
    k_conv1x1m<<<NN, 256, 0, stream>>>(r, bq_w, Qh);

    // ---- right branch -> K ----
    k_catbn_m<<<NN, 256, 0, stream>>>(x_right, conv2_w, conv2_b, bn_g, bn_b, bn_m, bn_v, u);
    k_conv3r<true,  false><<<dim3(256, 4, 2), 256, 0, stream>>>(u, Wp1, rb_b1, nullptr, y1);
    k_conv3r<false, true ><<<dim3(256, 4, 2), 256, 0, stream>>>(y1, Wp2, rb_b2, u, r);
    k_conv1x1m<<<NN, 256, 0, stream>>>(r, bs_w, Kh);

    // ---- fused attention tail: one direction per block, all blocks resident ----
    k_attn4<<<dim3(NN, 2), 512, 0, stream>>>(Qh, Kh, x_left, x_right, out_left, out_right);
}

// Round 9
// 484.477 us; speedup vs baseline: 1.5249x; 1.5249x over previous
//
#include <hip/hip_runtime.h>
#include <math.h>

// Problem constants
#define BB 4
#define CC 64
#define C2 128
#define HH 128
#define WW 256
#define NN (BB*HH)          // 512 row-pairs
#define EPSBN 1e-5f

typedef _Float16 f16;
typedef _Float16 half8 __attribute__((ext_vector_type(8)));
typedef float f32x4 __attribute__((ext_vector_type(4)));

// ---------------------------------------------------------------------------
// K0: weight prep — rb_w fp32 [o][icg][3][3] -> f16 [g][mo][ks*32+ic]
// ---------------------------------------------------------------------------
__global__ __launch_bounds__(256) void k_wprep(
    const float* __restrict__ w1, const float* __restrict__ w2,
    f16* __restrict__ wp1, f16* __restrict__ wp2)
{
    int g = blockIdx.x; int which = blockIdx.y;
    const float* src = which ? w2 : w1;
    f16* dst = which ? wp2 : wp1;
    for (int p = threadIdx.x; p < 9216; p += 256) {
        int mo = p / 288; int kr = p - mo*288;
        int ks = kr >> 5; int ic = kr & 31;
        dst[g*9216 + p] = (f16)src[((g*32 + mo)*32 + ic)*9 + ks];
    }
}

// ---------------------------------------------------------------------------
// K1: fused 1x1 conv (64->64) + concat + batchnorm -> u (channel-last f16)
// ---------------------------------------------------------------------------
__global__ __launch_bounds__(256) void k_catbn_m(
    const float* __restrict__ x, const float* __restrict__ cw, const float* __restrict__ cb,
    const float* __restrict__ g, const float* __restrict__ bb_, const float* __restrict__ m,
    const float* __restrict__ v, f16* __restrict__ u)
{
    __shared__ f16 Xl[256][72];   // [px][ic]
    __shared__ f16 Wl[64][72];    // [oc][ic]
    __shared__ float sS[64], sT[64], sS2[64], sT2[64];
    int n = blockIdx.x; int b = n >> 7; int h = n & 127; int t = threadIdx.x;
    for (int p = t; p < 2048; p += 256) {
        int idx = p * 2; int o = idx >> 6, i = idx & 63;
        union { f16 h[2]; unsigned int u1; } pr;
        pr.h[0] = (f16)cw[idx]; pr.h[1] = (f16)cw[idx + 1];
        *(unsigned int*)&Wl[o][i] = pr.u1;
    }
    if (t < 64) {
        float inv = rsqrtf(v[t] + EPSBN); float s = g[t] * inv;
        sS[t] = s; sT[t] = bb_[t] + s * (cb[t] - m[t]);
        float inv2 = rsqrtf(v[t + 64] + EPSBN); float s2 = g[t + 64] * inv2;
        sS2[t] = s2; sT2[t] = bb_[t + 64] - s2 * m[t + 64];
    }
    __syncthreads();
    f16* up = u + ((size_t)(n*256 + t)) * 128;
    for (int c8 = 0; c8 < 8; ++c8) {
        float xv8[8];
#pragma unroll
        for (int j = 0; j < 8; ++j)
            xv8[j] = x[(((b*64 + c8*8 + j)*128 + h) << 8) + t];
        union { f16 h[8]; uint4 v4; } pk;
#pragma unroll
        for (int j = 0; j < 8; ++j) {
            int c = c8*8 + j;
            pk.h[j] = (f16)(sS2[c]*xv8[j] + sT2[c]);
        }
        *(uint4*)(up + 64 + c8*8) = pk.v4;
#pragma unroll
        for (int j2 = 0; j2 < 4; ++j2) {
            union { f16 h[2]; unsigned int u1; } q;
            q.h[0] = (f16)xv8[j2*2]; q.h[1] = (f16)xv8[j2*2 + 1];
            *(unsigned int*)&Xl[t][c8*8 + j2*2] = q.u1;
        }
    }
    __syncthreads();
    int lane = t & 63, wv = t >> 6;
    int m16 = lane & 15, quad = lane >> 4;
    half8 af[4][2], bf[4][2];
#pragma unroll
    for (int mt = 0; mt < 4; ++mt)
#pragma unroll
        for (int kk = 0; kk < 2; ++kk)
            af[mt][kk] = *(const half8*)&Wl[mt*16 + m16][kk*32 + quad*8];
#pragma unroll
    for (int nt = 0; nt < 4; ++nt)
#pragma unroll
        for (int kk = 0; kk < 2; ++kk)
            bf[nt][kk] = *(const half8*)&Xl[wv*64 + nt*16 + m16][kk*32 + quad*8];
    f32x4 acc[4][4] = {};
#pragma unroll
    for (int mt = 0; mt < 4; ++mt)
#pragma unroll
        for (int nt = 0; nt < 4; ++nt) {
            acc[mt][nt] = __builtin_amdgcn_mfma_f32_16x16x32_f16(af[mt][0], bf[nt][0], acc[mt][nt], 0, 0, 0);
            acc[mt][nt] = __builtin_amdgcn_mfma_f32_16x16x32_f16(af[mt][1], bf[nt][1], acc[mt][nt], 0, 0, 0);
        }
#pragma unroll
    for (int mt = 0; mt < 4; ++mt) {
        int ocb = mt*16 + quad*4;
        float s4[4], t4[4];
        *(float4*)s4 = *(const float4*)&sS[ocb];
        *(float4*)t4 = *(const float4*)&sT[ocb];
#pragma unroll
        for (int nt = 0; nt < 4; ++nt) {
            int px = wv*64 + nt*16 + m16;
            union { f16 h[4]; uint2 u2; } ov;
#pragma unroll
            for (int r = 0; r < 4; ++r)
                ov.h[r] = (f16)(s4[r]*acc[mt][nt][r] + t4[r]);
            *(uint2*)(u + ((size_t)(n*256 + px))*128 + ocb) = ov.u2;
        }
    }
}

// ---------------------------------------------------------------------------
// K2/K3: grouped 3x3 conv, implicit-GEMM f16 MFMA.
// 2 output rows per block (4 staged rows, 41.6 KB LDS) -> 3 blocks/CU.
// ---------------------------------------------------------------------------
template<bool LEAKY, bool RES>
__global__ __launch_bounds__(256, 3) void k_conv3r(
    const f16* __restrict__ in, const f16* __restrict__ wp,
    const float* __restrict__ bias, const f16* __restrict__ res,
    f16* __restrict__ out)
{
    __shared__ f16 Xl[4*130*40];  // [row][px][ic] px-stride 40
    int b = blockIdx.x >> 6; int h0 = (blockIdx.x & 63) * 2;
    int g = blockIdx.y; int w0 = blockIdx.z * 128;
    int t = threadIdx.x;
    int lane = t & 63, wv = t >> 6;
    int m16 = lane & 15, quad = lane >> 4;
    const f16* wg = wp + g*9216;
    half8 af[2][9];
#pragma unroll
    for (int mt = 0; mt < 2; ++mt)
#pragma unroll
        for (int ks = 0; ks < 9; ++ks)
            af[mt][ks] = *(const half8*)(wg + (mt*16 + m16)*288 + ks*32 + quad*8);
    float bo[2][4];
#pragma unroll
    for (int mt = 0; mt < 2; ++mt)
#pragma unroll
        for (int r = 0; r < 4; ++r)
            bo[mt][r] = bias[g*32 + mt*16 + quad*4 + r];
    // ---- stage 4 input rows (h0-1 .. h0+2) ----
    for (int idx = t; idx < 2080; idx += 256) {
        int r = idx / 520; int rem = idx - r*520; int p = rem >> 2; int q = rem & 3;
        int hr = h0 + r - 1; int wg2 = w0 + p - 1;
        uint4 val = make_uint4(0,0,0,0);
        if ((unsigned)wg2 < 256u && (unsigned)hr < 128u)
            val = *(const uint4*)(in + ((size_t)((b*128 + hr)*256 + wg2))*128 + g*32 + q*8);
        *(uint4*)&Xl[(r*130 + p)*40 + q*8] = val;
    }
    __syncthreads();
    int px0 = wv*32 + m16;
#pragma unroll
    for (int rr = 0; rr < 2; ++rr) {
        f32x4 acc[2][2] = {};
#pragma unroll
        for (int ks = 0; ks < 9; ++ks) {
            int ky = ks / 3, kx = ks - ky*3;
            half8 bf0 = *(const half8*)&Xl[((rr + ky)*130 + px0 + kx)*40 + quad*8];
            half8 bf1 = *(const half8*)&Xl[((rr + ky)*130 + px0 + 16 + kx)*40 + quad*8];
            acc[0][0] = __builtin_amdgcn_mfma_f32_16x16x32_f16(af[0][ks], bf0, acc[0][0], 0, 0, 0);
            acc[0][1] = __builtin_amdgcn_mfma_f32_16x16x32_f16(af[0][ks], bf1, acc[0][1], 0, 0, 0);
            acc[1][0] = __builtin_amdgcn_mfma_f32_16x16x32_f16(af[1][ks], bf0, acc[1][0], 0, 0, 0);
            acc[1][1] = __builtin_amdgcn_mfma_f32_16x16x32_f16(af[1][ks], bf1, acc[1][1], 0, 0, 0);
        }
        int h = h0 + rr;
#pragma unroll
        for (int mt = 0; mt < 2; ++mt)
#pragma unroll
            for (int nt = 0; nt < 2; ++nt) {
                int px = w0 + wv*32 + nt*16 + m16;
                int oc = g*32 + mt*16 + quad*4;
                size_t off = ((size_t)((b*128 + h)*256 + px))*128 + oc;
                float rv4[4] = {0.f, 0.f, 0.f, 0.f};
                if (RES) {
                    union { f16 h[4]; uint2 v2; } rrd;
                    rrd.v2 = *(const uint2*)(res + off);
#pragma unroll
                    for (int r = 0; r < 4; ++r) rv4[r] = (float)rrd.h[r];
                }
                union { f16 h[4]; uint2 v2; } ov;
#pragma unroll
                for (int r = 0; r < 4; ++r) {
                    float y = acc[mt][nt][r] + bo[mt][r];
                    if (LEAKY) y = y > 0.f ? y : 0.1f*y;
                    if (RES) y += rv4[r];
                    ov.h[r] = (f16)y;
                }
                *(uint2*)(out + off) = ov.v2;
            }
    }
}

// ---------------------------------------------------------------------------
// K4: grouped 1x1 conv (128->64, groups=2) + row-mean subtraction, MFMA f16.
// ---------------------------------------------------------------------------
__global__ __launch_bounds__(256, 2) void k_conv1x1m(
    const f16* __restrict__ in, const float* __restrict__ wgt,
    f16* __restrict__ outq)
{
    __shared__ f16 Xl[256][72];       // one group's 64 ic (+8 pad)
    __shared__ f16 Wl[64][72];        // all 64 oc, within-group ic
    __shared__ float partial[4][64];  // per-wave px-sums per oc
    __shared__ float meanS[64];
    int n = blockIdx.x; int t = threadIdx.x;
    int lane = t & 63, wv = t >> 6;
    int m16 = lane & 15, quad = lane >> 4;
    for (int p = t; p < 2048; p += 256) {
        int idx = p * 2; int o = idx >> 6, i = idx & 63;
        union { f16 h[2]; unsigned int u1; } pr;
        pr.h[0] = (f16)wgt[idx]; pr.h[1] = (f16)wgt[idx + 1];
        *(unsigned int*)&Wl[o][i] = pr.u1;
    }
    f32x4 acc[4][4] = {};             // [oc tile 0..3][px tile 0..3]
    const f16* rp = in + ((size_t)n*256 + t)*128;
    for (int g = 0; g < 2; ++g) {
#pragma unroll
        for (int i8 = 0; i8 < 8; ++i8)
            *(uint4*)&Xl[t][i8*8] = *(const uint4*)(rp + g*64 + i8*8);
        __syncthreads();
        half8 af[2][2], bf[4][2];
#pragma unroll
        for (int ml = 0; ml < 2; ++ml)
#pragma unroll
            for (int kk = 0; kk < 2; ++kk)
                af[ml][kk] = *(const half8*)&Wl[g*32 + ml*16 + m16][kk*32 + quad*8];
#pragma unroll
        for (int nt = 0; nt < 4; ++nt)
#pragma unroll
            for (int kk = 0; kk < 2; ++kk)
                bf[nt][kk] = *(const half8*)&Xl[wv*64 + nt*16 + m16][kk*32 + quad*8];
#pragma unroll
        for (int ml = 0; ml < 2; ++ml)
#pragma unroll
            for (int nt = 0; nt < 4; ++nt) {
                int mt = g*2 + ml;
                acc[mt][nt] = __builtin_amdgcn_mfma_f32_16x16x32_f16(af[ml][0], bf[nt][0], acc[mt][nt], 0, 0, 0);
                acc[mt][nt] = __builtin_amdgcn_mfma_f32_16x16x32_f16(af[ml][1], bf[nt][1], acc[mt][nt], 0, 0, 0);
            }
        __syncthreads();
    }
#pragma unroll
    for (int mt = 0; mt < 4; ++mt)
#pragma unroll
        for (int r = 0; r < 4; ++r) {
            float s = acc[mt][0][r] + acc[mt][1][r] + acc[mt][2][r] + acc[mt][3][r];
            s += __shfl_xor(s, 1); s += __shfl_xor(s, 2);
            s += __shfl_xor(s, 4); s += __shfl_xor(s, 8);
            if (m16 == 0) partial[wv][mt*16 + quad*4 + r] = s;
        }
    __syncthreads();
    if (t < 64)
        meanS[t] = (partial[0][t] + partial[1][t] + partial[2][t] + partial[3][t]) * (1.0f/256.0f);
    __syncthreads();
    f16* qp = outq + ((size_t)n*256)*64;
#pragma unroll
    for (int mt = 0; mt < 4; ++mt) {
        int ocb = mt*16 + quad*4;
        float m4[4]; *(float4*)m4 = *(const float4*)&meanS[ocb];
#pragma unroll
        for (int nt = 0; nt < 4; ++nt) {
            int px = wv*64 + nt*16 + m16;
            union { f16 h[4]; uint2 u2; } ov;
#pragma unroll
            for (int r = 0; r < 4; ++r)
                ov.h[r] = (f16)(acc[mt][nt][r] - m4[r]);
            *(uint2*)(qp + (size_t)px*64 + ocb) = ov.u2;
        }
    }
}

// ---------------------------------------------------------------------------
// K5: fused attention, no S-buffer, ONE direction per block.
// grid (512, 2): blockIdx.y = 0 -> left output, 1 -> right (S^T recompute).
// LDS 30 KB; __launch_bounds__(512,4) -> VGPR cap 128, compiler uses ~64
// (R7-verified, no spills) -> HW can co-schedule 4 blocks/CU, all 1024
// blocks resident.  R8's (512,8) forced VGPR=32 -> 1.5 GB scratch spills.
// ---------------------------------------------------------------------------
__device__ __forceinline__ void attn_pass3(
    const f16* __restrict__ Ap, const f16* __restrict__ Bp, char* pool,
    const float* __restrict__ myM, const float* __restrict__ myI,  // by row r
    const float* __restrict__ oM,  const float* __restrict__ oI,   // by col j
    const float* __restrict__ xB, const float* __restrict__ xP,
    float* __restrict__ outp, int b, int h, int t)
{
    f16 (*Pl)[40] = (f16(*)[40])pool;               // rows +2 (window pad)
    f16 (*Xl)[40] = (f16(*)[40])(pool + 20800);
    float* scr = (float*)(pool + 20800);            // overlays Xl (post-loop)
    float* Vv  = (float*)(pool + 22848);
    int lane = t & 63, wv = t >> 6;
    int m16 = lane & 15, quad = lane >> 4;
    int W = wv * 32;
    int r = t & 255, hc = t >> 8;
    int cbase = hc * 16;
    float rm = myM[r], ri = myI[r];
    int xc = t >> 3, xj = (t & 7) * 4;
    const float* xg = xB + ((size_t)(b*64 + xc)*128 + h)*256;
    // A fragments for this wave's 32 rows (constant across chunks)
    half8 af[2][2];
#pragma unroll
    for (int mt = 0; mt < 2; ++mt)
#pragma unroll
        for (int kk = 0; kk < 2; ++kk)
            af[mt][kk] = *(const half8*)(Ap + (size_t)(W + mt*16 + m16)*64 + kk*32 + quad*8);
    f32x4 acc[2][4] = {};
    float vacc = 0.f;
    for (int kc = 0; kc < 256; kc += 32) {
        // ---- recompute S slab (32 rows/wave x 32 chunk cols) ----
        half8 bf[2][2];
#pragma unroll
        for (int nt = 0; nt < 2; ++nt)
#pragma unroll
            for (int kk = 0; kk < 2; ++kk)
                bf[nt][kk] = *(const half8*)(Bp + (size_t)(kc + nt*16 + m16)*64 + kk*32 + quad*8);
        f32x4 s1[2][2] = {};
#pragma unroll
        for (int mt = 0; mt < 2; ++mt)
#pragma unroll
            for (int nt = 0; nt < 2; ++nt) {
                s1[mt][nt] = __builtin_amdgcn_mfma_f32_16x16x32_f16(af[mt][0], bf[nt][0], s1[mt][nt], 0, 0, 0);
                s1[mt][nt] = __builtin_amdgcn_mfma_f32_16x16x32_f16(af[mt][1], bf[nt][1], s1[mt][nt], 0, 0, 0);
            }
        // stage Xl chunk
        {
            float4 x4 = *(const float4*)(xg + kc + xj);
            union { f16 h[4]; uint2 v2; } px;
            px.h[0] = (f16)x4.x; px.h[1] = (f16)x4.y;
            px.h[2] = (f16)x4.z; px.h[3] = (f16)x4.w;
            *(uint2*)&Xl[xc][xj] = px.v2;
        }
        // scatter raw S (C-layout) into Pl
#pragma unroll
        for (int mt = 0; mt < 2; ++mt)
#pragma unroll
            for (int nt = 0; nt < 2; ++nt)
#pragma unroll
                for (int rr = 0; rr < 4; ++rr)
                    Pl[W + mt*16 + quad*4 + rr + 2][nt*16 + m16] = (f16)s1[mt][nt][rr];
        __syncthreads();
        // ---- row pass: raw -> P (in place), keep raw in regs for Bv ----
        float sraw[16];
        char* pb = (char*)&Pl[r + 2][cbase];
        {
            half8 v0 = *(const half8*)pb;
            half8 v1 = *(const half8*)(pb + 16);
            half8 p0, p1;
#pragma unroll
            for (int e = 0; e < 8; ++e) {
                sraw[e] = (float)v0[e];
                p0[e] = (f16)(__expf(sraw[e] - rm) * ri);
            }
#pragma unroll
            for (int e = 0; e < 8; ++e) {
                sraw[8 + e] = (float)v1[e];
                p1[e] = (f16)(__expf(sraw[8 + e] - rm) * ri);
            }
            *(half8*)pb = p0; *(half8*)(pb + 16) = p1;
        }
        __syncthreads();
        // ---- window + V partial ----
#pragma unroll
        for (int j8 = 0; j8 < 2; ++j8) {
            const char* wb = (const char*)&Pl[r][cbase + j8*8];
            half8 w0 = *(const half8*)(wb);
            half8 w1 = *(const half8*)(wb + 80);
            half8 w2 = *(const half8*)(wb + 160);
            half8 w3 = *(const half8*)(wb + 240);
            half8 w4 = *(const half8*)(wb + 320);
            half8 win = w0 + w1 + w2 + w3 + w4;
#pragma unroll
            for (int e = 0; e < 8; ++e) {
                int j = kc + cbase + j8*8 + e;
                float Bv = __expf(sraw[j8*8 + e] - oM[j]) * oI[j];
                vacc = fmaf((float)win[e], Bv, vacc);
            }
        }
        // ---- PV MFMA ----
        half8 pa[2], xb_[4];
#pragma unroll
        for (int mt = 0; mt < 2; ++mt)
            pa[mt] = *(const half8*)((const char*)&Pl[W + mt*16 + m16 + 2][0] + quad*16);
#pragma unroll
        for (int nt = 0; nt < 4; ++nt)
            xb_[nt] = *(const half8*)((const char*)&Xl[nt*16 + m16][0] + quad*16);
#pragma unroll
        for (int mt = 0; mt < 2; ++mt)
#pragma unroll
            for (int nt = 0; nt < 4; ++nt)
                acc[mt][nt] = __builtin_amdgcn_mfma_f32_16x16x32_f16(pa[mt], xb_[nt], acc[mt][nt], 0, 0, 0);
        __syncthreads();
    }
    // ---- V merge + epilogue ----
    scr[hc*256 + r] = vacc;
    __syncthreads();
    if (t < 256) Vv[t] = scr[t] + scr[256 + t];
    __syncthreads();
#pragma unroll
    for (int mt = 0; mt < 2; ++mt) {
        int i0 = W + mt*16 + quad*4;
        float v4[4];
        *(float4*)v4 = *(const float4*)&Vv[i0];
        float tv[4];
#pragma unroll
        for (int rr = 0; rr < 4; ++rr) tv[rr] = tanhf(5.f*v4[rr]);
#pragma unroll
        for (int nt = 0; nt < 4; ++nt) {
            int c = nt*16 + m16;
            size_t base = (((size_t)(b*64 + c)*128 + h) << 8) + i0;
            float xp4[4]; *(float4*)xp4 = *(const float4*)&xP[base];
            float o4[4];
#pragma unroll
            for (int rr = 0; rr < 4; ++rr)
                o4[rr] = xp4[rr]*(1.f - tv[rr]) + acc[mt][nt][rr]*tv[rr];
            *(float4*)&outp[base] = *(float4*)o4;
        }
    }
}

__global__ __launch_bounds__(512, 4) void k_attn4(
    const f16* __restrict__ Q, const f16* __restrict__ K,
    const float* __restrict__ xl, const float* __restrict__ xr,
    float* __restrict__ outL, float* __restrict__ outR)
{
    __shared__ __align__(16) char pool[25920];  // Pl/Xl ∪ colM/colS ∪ scr/Vv
    __shared__ float rmS[256], riS[256], cmS[256], ciS[256];
    float* colM = (float*)pool;            // [8][256] per-wave col partial max
    float* colS = (float*)(pool + 8192);   // [8][256] per-wave col partial sum
    int n = blockIdx.x; int b = n >> 7; int h = n & 127;
    int pass = blockIdx.y;
    int t = threadIdx.x;
    int lane = t & 63, wv = t >> 6;
    int m16 = lane & 15, quad = lane >> 4;
    int W = wv * 32;

    // ---- phase 1: S = Q·K^T, stats only (no store) ----
    const f16* ag = Q + (size_t)n*16384;
    const f16* bg = K + (size_t)n*16384;
    half8 af1[2][2];
#pragma unroll
    for (int mt = 0; mt < 2; ++mt)
#pragma unroll
        for (int kk = 0; kk < 2; ++kk)
            af1[mt][kk] = *(const half8*)(ag + (size_t)(W + mt*16 + m16)*64 + kk*32 + quad*8);
    float rowm[8], rows_[8];
#pragma unroll
    for (int i = 0; i < 8; ++i) { rowm[i] = -1e30f; rows_[i] = 0.f; }
    for (int jc = 0; jc < 256; jc += 64) {
        half8 bf1[4][2];
#pragma unroll
        for (int nt = 0; nt < 4; ++nt)
#pragma unroll
            for (int kk = 0; kk < 2; ++kk)
                bf1[nt][kk] = *(const half8*)(bg + (size_t)(jc + nt*16 + m16)*64 + kk*32 + quad*8);
        f32x4 acc1[2][4] = {};
#pragma unroll
        for (int mt = 0; mt < 2; ++mt)
#pragma unroll
            for (int nt = 0; nt < 4; ++nt) {
                acc1[mt][nt] = __builtin_amdgcn_mfma_f32_16x16x32_f16(af1[mt][0], bf1[nt][0], acc1[mt][nt], 0, 0, 0);
                acc1[mt][nt] = __builtin_amdgcn_mfma_f32_16x16x32_f16(af1[mt][1], bf1[nt][1], acc1[mt][nt], 0, 0, 0);
            }
        // round to f16 so stats match the recomputed (rounded) S exactly
#pragma unroll
        for (int mt = 0; mt < 2; ++mt)
#pragma unroll
            for (int nt = 0; nt < 4; ++nt)
#pragma unroll
                for (int r = 0; r < 4; ++r)
                    acc1[mt][nt][r] = (float)(f16)acc1[mt][nt][r];
        // row stats: reduce over 4 in-lane cols + 16 m16-lanes, online across jc
#pragma unroll
        for (int mt = 0; mt < 2; ++mt)
#pragma unroll
            for (int r = 0; r < 4; ++r) {
                float lm = fmaxf(fmaxf(acc1[mt][0][r], acc1[mt][1][r]),
                                 fmaxf(acc1[mt][2][r], acc1[mt][3][r]));
                lm = fmaxf(lm, __shfl_xor(lm, 1));
                lm = fmaxf(lm, __shfl_xor(lm, 2));
                lm = fmaxf(lm, __shfl_xor(lm, 4));
                lm = fmaxf(lm, __shfl_xor(lm, 8));
                float le = __expf(acc1[mt][0][r] - lm) + __expf(acc1[mt][1][r] - lm)
                         + __expf(acc1[mt][2][r] - lm) + __expf(acc1[mt][3][r] - lm);
                le += __shfl_xor(le, 1); le += __shfl_xor(le, 2);
                le += __shfl_xor(le, 4); le += __shfl_xor(le, 8);
                int idx = mt*4 + r;
                float nm = fmaxf(rowm[idx], lm);
                rows_[idx] = rows_[idx]*__expf(rowm[idx] - nm) + le*__expf(lm - nm);
                rowm[idx] = nm;
            }
        // col stats: reduce over 8 in-lane rows + 4 quads -> per-wave partial
#pragma unroll
        for (int nt = 0; nt < 4; ++nt) {
            float lm = acc1[0][nt][0];
#pragma unroll
            for (int r = 1; r < 4; ++r) lm = fmaxf(lm, acc1[0][nt][r]);
#pragma unroll
            for (int r = 0; r < 4; ++r) lm = fmaxf(lm, acc1[1][nt][r]);
            lm = fmaxf(lm, __shfl_xor(lm, 16));
            lm = fmaxf(lm, __shfl_xor(lm, 32));
            float le = 0.f;
#pragma unroll
            for (int mt2 = 0; mt2 < 2; ++mt2)
#pragma unroll
                for (int r = 0; r < 4; ++r) le += __expf(acc1[mt2][nt][r] - lm);
            le += __shfl_xor(le, 16); le += __shfl_xor(le, 32);
            if (quad == 0) {
                int col = jc + nt*16 + m16;
                colM[wv*256 + col] = lm;
                colS[wv*256 + col] = le;
            }
        }
    }
    if (m16 == 0) {
#pragma unroll
        for (int mt = 0; mt < 2; ++mt)
#pragma unroll
            for (int r = 0; r < 4; ++r) {
                int row = W + mt*16 + quad*4 + r;
                rmS[row] = rowm[mt*4 + r];
                riS[row] = 1.0f / rows_[mt*4 + r];
            }
    }
    __syncthreads();
    // merge 8 per-wave col partials
    if (t < 256) {
        float m = colM[t], s = colS[t];
#pragma unroll
        for (int w = 1; w < 8; ++w) {
            float m2 = colM[w*256 + t], s2 = colS[w*256 + t];
            float nm = fmaxf(m, m2);
            s = s*__expf(m - nm) + s2*__expf(m2 - nm);
            m = nm;
        }
        cmS[t] = m; ciS[t] = 1.0f / s;
    }
    __syncthreads();
    // zero Pl window-pad rows (0,1 and 258,259) — pool now free
    if (t < 10)       *(uint4*)(pool + t*16)              = make_uint4(0,0,0,0);
    else if (t < 20)  *(uint4*)(pool + 20640 + (t-10)*16) = make_uint4(0,0,0,0);

    // ---- one direction per block (operands picked by pass) ----
    const f16*  Ap = pass ? bg : ag;
    const f16*  Bp = pass ? ag : bg;
    const float* mM = pass ? cmS : rmS;
    const float* mI = pass ? ciS : riS;
    const float* oM = pass ? rmS : cmS;
    const float* oI = pass ? riS : ciS;
    const float* xB = pass ? xl : xr;
    const float* xP = pass ? xr : xl;
    float* outp     = pass ? outR : outL;
    attn_pass3(Ap, Bp, pool, mM, mI, oM, oI, xB, xP, outp, b, h, t);
}

// ---------------------------------------------------------------------------
extern "C" void kernel_launch(void* const* d_in, const int* in_sizes, int n_in,
                              void* d_out, int out_size, void* d_ws, size_t ws_size,
                              hipStream_t stream)
{
    const float* x_left  = (const float*)d_in[0];
    const float* x_right = (const float*)d_in[1];
    const float* conv1_w = (const float*)d_in[2];
    const float* conv1_b = (const float*)d_in[3];
    const float* conv2_w = (const float*)d_in[4];
    const float* conv2_b = (const float*)d_in[5];
    const float* bn_g    = (const float*)d_in[6];
    const float* bn_b    = (const float*)d_in[7];
    const float* bn_m    = (const float*)d_in[8];
    const float* bn_v    = (const float*)d_in[9];
    const float* rb_w1   = (const float*)d_in[10];
    const float* rb_b1   = (const float*)d_in[11];
    const float* rb_w2   = (const float*)d_in[12];
    const float* rb_b2   = (const float*)d_in[13];
    const float* bq_w    = (const float*)d_in[14];
    const float* bs_w    = (const float*)d_in[16];

    f16* W16 = (f16*)d_ws;
    f16* u  = W16;                       // 16,777,216 els
    f16* y1 = W16 + 16777216;            // 16,777,216
    f16* r  = W16 + 33554432;            // 16,777,216
    f16* Qh = W16 + 67108864;            //  8,388,608
    f16* Kh = W16 + 75497472;            //  8,388,608
    f16* Wp1 = W16 + 84934656;           // 36,864 els (prepped rb_w1)
    f16* Wp2 = W16 + 84971520;           // 36,864 els (prepped rb_w2)

    float* out_left  = (float*)d_out;
    float* out_right = (float*)d_out + 8388608;

    // ---- weight prep (once per launch) ----
    k_wprep<<<dim3(4, 2), 256, 0, stream>>>(rb_w1, rb_w2, Wp1, Wp2);

    // ---- left branch -> Q ----
    k_catbn_m<<<NN, 256, 0, stream>>>(x_left, conv1_w, conv1_b, bn_g, bn_b, bn_m, bn_v, u);
    k_conv3r<true,  false><<<dim3(256, 4, 2), 256, 0, stream>>>(u, Wp1, rb_b1, nullptr, y1);
    k_conv3r<false, true ><<<dim3(256, 4, 2), 256, 0, stream>>>(y1, Wp2, rb_b2, u, r);
    k_conv1x1m<<<NN, 256, 0, stream>>>(r, bq_w, Qh);

    // ---- right branch -> K ----
    k_catbn_m<<<NN, 256, 0, stream>>>(x_right, conv2_w, conv2_b, bn_g, bn_b, bn_m, bn_v, u);
    k_conv3r<true,  false><<<dim3(256, 4, 2), 256, 0, stream>>>(u, Wp1, rb_b1, nullptr, y1);
    k_conv3r<false, true ><<<dim3(256, 4, 2), 256, 0, stream>>>(y1, Wp2, rb_b2, u, r);
    k_conv1x1m<<<NN, 256, 0, stream>>>(r, bs_w, Kh);

    // ---- fused attention tail: one direction per block, all blocks resident ----
    k_attn4<<<dim3(NN, 2), 512, 0, stream>>>(Qh, Kh, x_left, x_right, out_left, out_right);
}

// Round 10
// 470.588 us; speedup vs baseline: 1.5699x; 1.0295x over previous
//
#include <hip/hip_runtime.h>
#include <math.h>

// Problem constants
#define BB 4
#define CC 64
#define C2 128
#define HH 128
#define WW 256
#define NN (BB*HH)          // 512 row-pairs
#define EPSBN 1e-5f

typedef _Float16 f16;
typedef _Float16 half8 __attribute__((ext_vector_type(8)));
typedef float f32x4 __attribute__((ext_vector_type(4)));

// ---------------------------------------------------------------------------
// K0: weight prep — rb_w fp32 [o][icg][3][3] -> f16 [g][mo][ks*32+ic]
// ---------------------------------------------------------------------------
__global__ __launch_bounds__(256) void k_wprep(
    const float* __restrict__ w1, const float* __restrict__ w2,
    f16* __restrict__ wp1, f16* __restrict__ wp2)
{
    int g = blockIdx.x; int which = blockIdx.y;
    const float* src = which ? w2 : w1;
    f16* dst = which ? wp2 : wp1;
    for (int p = threadIdx.x; p < 9216; p += 256) {
        int mo = p / 288; int kr = p - mo*288;
        int ks = kr >> 5; int ic = kr & 31;
        dst[g*9216 + p] = (f16)src[((g*32 + mo)*32 + ic)*9 + ks];
    }
}

// ---------------------------------------------------------------------------
// K1: fused 1x1 conv (64->64) + concat + batchnorm -> u (channel-last f16)
// ---------------------------------------------------------------------------
__global__ __launch_bounds__(256) void k_catbn_m(
    const float* __restrict__ x, const float* __restrict__ cw, const float* __restrict__ cb,
    const float* __restrict__ g, const float* __restrict__ bb_, const float* __restrict__ m,
    const float* __restrict__ v, f16* __restrict__ u)
{
    __shared__ f16 Xl[256][72];   // [px][ic]
    __shared__ f16 Wl[64][72];    // [oc][ic]
    __shared__ float sS[64], sT[64], sS2[64], sT2[64];
    int n = blockIdx.x; int b = n >> 7; int h = n & 127; int t = threadIdx.x;
    for (int p = t; p < 2048; p += 256) {
        int idx = p * 2; int o = idx >> 6, i = idx & 63;
        union { f16 h[2]; unsigned int u1; } pr;
        pr.h[0] = (f16)cw[idx]; pr.h[1] = (f16)cw[idx + 1];
        *(unsigned int*)&Wl[o][i] = pr.u1;
    }
    if (t < 64) {
        float inv = rsqrtf(v[t] + EPSBN); float s = g[t] * inv;
        sS[t] = s; sT[t] = bb_[t] + s * (cb[t] - m[t]);
        float inv2 = rsqrtf(v[t + 64] + EPSBN); float s2 = g[t + 64] * inv2;
        sS2[t] = s2; sT2[t] = bb_[t + 64] - s2 * m[t + 64];
    }
    __syncthreads();
    f16* up = u + ((size_t)(n*256 + t)) * 128;
    for (int c8 = 0; c8 < 8; ++c8) {
        float xv8[8];
#pragma unroll
        for (int j = 0; j < 8; ++j)
            xv8[j] = x[(((b*64 + c8*8 + j)*128 + h) << 8) + t];
        union { f16 h[8]; uint4 v4; } pk;
#pragma unroll
        for (int j = 0; j < 8; ++j) {
            int c = c8*8 + j;
            pk.h[j] = (f16)(sS2[c]*xv8[j] + sT2[c]);
        }
        *(uint4*)(up + 64 + c8*8) = pk.v4;
#pragma unroll
        for (int j2 = 0; j2 < 4; ++j2) {
            union { f16 h[2]; unsigned int u1; } q;
            q.h[0] = (f16)xv8[j2*2]; q.h[1] = (f16)xv8[j2*2 + 1];
            *(unsigned int*)&Xl[t][c8*8 + j2*2] = q.u1;
        }
    }
    __syncthreads();
    int lane = t & 63, wv = t >> 6;
    int m16 = lane & 15, quad = lane >> 4;
    half8 af[4][2], bf[4][2];
#pragma unroll
    for (int mt = 0; mt < 4; ++mt)
#pragma unroll
        for (int kk = 0; kk < 2; ++kk)
            af[mt][kk] = *(const half8*)&Wl[mt*16 + m16][kk*32 + quad*8];
#pragma unroll
    for (int nt = 0; nt < 4; ++nt)
#pragma unroll
        for (int kk = 0; kk < 2; ++kk)
            bf[nt][kk] = *(const half8*)&Xl[wv*64 + nt*16 + m16][kk*32 + quad*8];
    f32x4 acc[4][4] = {};
#pragma unroll
    for (int mt = 0; mt < 4; ++mt)
#pragma unroll
        for (int nt = 0; nt < 4; ++nt) {
            acc[mt][nt] = __builtin_amdgcn_mfma_f32_16x16x32_f16(af[mt][0], bf[nt][0], acc[mt][nt], 0, 0, 0);
            acc[mt][nt] = __builtin_amdgcn_mfma_f32_16x16x32_f16(af[mt][1], bf[nt][1], acc[mt][nt], 0, 0, 0);
        }
#pragma unroll
    for (int mt = 0; mt < 4; ++mt) {
        int ocb = mt*16 + quad*4;
        float s4[4], t4[4];
        *(float4*)s4 = *(const float4*)&sS[ocb];
        *(float4*)t4 = *(const float4*)&sT[ocb];
#pragma unroll
        for (int nt = 0; nt < 4; ++nt) {
            int px = wv*64 + nt*16 + m16;
            union { f16 h[4]; uint2 u2; } ov;
#pragma unroll
            for (int r = 0; r < 4; ++r)
                ov.h[r] = (f16)(s4[r]*acc[mt][nt][r] + t4[r]);
            *(uint2*)(u + ((size_t)(n*256 + px))*128 + ocb) = ov.u2;
        }
    }
}

// ---------------------------------------------------------------------------
// K2/K3: grouped 3x3 conv, implicit-GEMM f16 MFMA.
// 2 output rows per block (4 staged rows, 41.6 KB LDS) -> 3 blocks/CU.
// ---------------------------------------------------------------------------
template<bool LEAKY, bool RES>
__global__ __launch_bounds__(256, 3) void k_conv3r(
    const f16* __restrict__ in, const f16* __restrict__ wp,
    const float* __restrict__ bias, const f16* __restrict__ res,
    f16* __restrict__ out)
{
    __shared__ f16 Xl[4*130*40];  // [row][px][ic] px-stride 40
    int b = blockIdx.x >> 6; int h0 = (blockIdx.x & 63) * 2;
    int g = blockIdx.y; int w0 = blockIdx.z * 128;
    int t = threadIdx.x;
    int lane = t & 63, wv = t >> 6;
    int m16 = lane & 15, quad = lane >> 4;
    const f16* wg = wp + g*9216;
    half8 af[2][9];
#pragma unroll
    for (int mt = 0; mt < 2; ++mt)
#pragma unroll
        for (int ks = 0; ks < 9; ++ks)
            af[mt][ks] = *(const half8*)(wg + (mt*16 + m16)*288 + ks*32 + quad*8);
    float bo[2][4];
#pragma unroll
    for (int mt = 0; mt < 2; ++mt)
#pragma unroll
        for (int r = 0; r < 4; ++r)
            bo[mt][r] = bias[g*32 + mt*16 + quad*4 + r];
    // ---- stage 4 input rows (h0-1 .. h0+2) ----
    for (int idx = t; idx < 2080; idx += 256) {
        int r = idx / 520; int rem = idx - r*520; int p = rem >> 2; int q = rem & 3;
        int hr = h0 + r - 1; int wg2 = w0 + p - 1;
        uint4 val = make_uint4(0,0,0,0);
        if ((unsigned)wg2 < 256u && (unsigned)hr < 128u)
            val = *(const uint4*)(in + ((size_t)((b*128 + hr)*256 + wg2))*128 + g*32 + q*8);
        *(uint4*)&Xl[(r*130 + p)*40 + q*8] = val;
    }
    __syncthreads();
    int px0 = wv*32 + m16;
#pragma unroll
    for (int rr = 0; rr < 2; ++rr) {
        f32x4 acc[2][2] = {};
#pragma unroll
        for (int ks = 0; ks < 9; ++ks) {
            int ky = ks / 3, kx = ks - ky*3;
            half8 bf0 = *(const half8*)&Xl[((rr + ky)*130 + px0 + kx)*40 + quad*8];
            half8 bf1 = *(const half8*)&Xl[((rr + ky)*130 + px0 + 16 + kx)*40 + quad*8];
            acc[0][0] = __builtin_amdgcn_mfma_f32_16x16x32_f16(af[0][ks], bf0, acc[0][0], 0, 0, 0);
            acc[0][1] = __builtin_amdgcn_mfma_f32_16x16x32_f16(af[0][ks], bf1, acc[0][1], 0, 0, 0);
            acc[1][0] = __builtin_amdgcn_mfma_f32_16x16x32_f16(af[1][ks], bf0, acc[1][0], 0, 0, 0);
            acc[1][1] = __builtin_amdgcn_mfma_f32_16x16x32_f16(af[1][ks], bf1, acc[1][1], 0, 0, 0);
        }
        int h = h0 + rr;
#pragma unroll
        for (int mt = 0; mt < 2; ++mt)
#pragma unroll
            for (int nt = 0; nt < 2; ++nt) {
                int px = w0 + wv*32 + nt*16 + m16;
                int oc = g*32 + mt*16 + quad*4;
                size_t off = ((size_t)((b*128 + h)*256 + px))*128 + oc;
                float rv4[4] = {0.f, 0.f, 0.f, 0.f};
                if (RES) {
                    union { f16 h[4]; uint2 v2; } rrd;
                    rrd.v2 = *(const uint2*)(res + off);
#pragma unroll
                    for (int r = 0; r < 4; ++r) rv4[r] = (float)rrd.h[r];
                }
                union { f16 h[4]; uint2 v2; } ov;
#pragma unroll
                for (int r = 0; r < 4; ++r) {
                    float y = acc[mt][nt][r] + bo[mt][r];
                    if (LEAKY) y = y > 0.f ? y : 0.1f*y;
                    if (RES) y += rv4[r];
                    ov.h[r] = (f16)y;
                }
                *(uint2*)(out + off) = ov.v2;
            }
    }
}

// ---------------------------------------------------------------------------
// K4: grouped 1x1 conv (128->64, groups=2) + row-mean subtraction, MFMA f16.
// ---------------------------------------------------------------------------
__global__ __launch_bounds__(256, 2) void k_conv1x1m(
    const f16* __restrict__ in, const float* __restrict__ wgt,
    f16* __restrict__ outq)
{
    __shared__ f16 Xl[256][72];       // one group's 64 ic (+8 pad)
    __shared__ f16 Wl[64][72];        // all 64 oc, within-group ic
    __shared__ float partial[4][64];  // per-wave px-sums per oc
    __shared__ float meanS[64];
    int n = blockIdx.x; int t = threadIdx.x;
    int lane = t & 63, wv = t >> 6;
    int m16 = lane & 15, quad = lane >> 4;
    for (int p = t; p < 2048; p += 256) {
        int idx = p * 2; int o = idx >> 6, i = idx & 63;
        union { f16 h[2]; unsigned int u1; } pr;
        pr.h[0] = (f16)wgt[idx]; pr.h[1] = (f16)wgt[idx + 1];
        *(unsigned int*)&Wl[o][i] = pr.u1;
    }
    f32x4 acc[4][4] = {};             // [oc tile 0..3][px tile 0..3]
    const f16* rp = in + ((size_t)n*256 + t)*128;
    for (int g = 0; g < 2; ++g) {
#pragma unroll
        for (int i8 = 0; i8 < 8; ++i8)
            *(uint4*)&Xl[t][i8*8] = *(const uint4*)(rp + g*64 + i8*8);
        __syncthreads();
        half8 af[2][2], bf[4][2];
#pragma unroll
        for (int ml = 0; ml < 2; ++ml)
#pragma unroll
            for (int kk = 0; kk < 2; ++kk)
                af[ml][kk] = *(const half8*)&Wl[g*32 + ml*16 + m16][kk*32 + quad*8];
#pragma unroll
        for (int nt = 0; nt < 4; ++nt)
#pragma unroll
            for (int kk = 0; kk < 2; ++kk)
                bf[nt][kk] = *(const half8*)&Xl[wv*64 + nt*16 + m16][kk*32 + quad*8];
#pragma unroll
        for (int ml = 0; ml < 2; ++ml)
#pragma unroll
            for (int nt = 0; nt < 4; ++nt) {
                int mt = g*2 + ml;
                acc[mt][nt] = __builtin_amdgcn_mfma_f32_16x16x32_f16(af[ml][0], bf[nt][0], acc[mt][nt], 0, 0, 0);
                acc[mt][nt] = __builtin_amdgcn_mfma_f32_16x16x32_f16(af[ml][1], bf[nt][1], acc[mt][nt], 0, 0, 0);
            }
        __syncthreads();
    }
#pragma unroll
    for (int mt = 0; mt < 4; ++mt)
#pragma unroll
        for (int r = 0; r < 4; ++r) {
            float s = acc[mt][0][r] + acc[mt][1][r] + acc[mt][2][r] + acc[mt][3][r];
            s += __shfl_xor(s, 1); s += __shfl_xor(s, 2);
            s += __shfl_xor(s, 4); s += __shfl_xor(s, 8);
            if (m16 == 0) partial[wv][mt*16 + quad*4 + r] = s;
        }
    __syncthreads();
    if (t < 64)
        meanS[t] = (partial[0][t] + partial[1][t] + partial[2][t] + partial[3][t]) * (1.0f/256.0f);
    __syncthreads();
    f16* qp = outq + ((size_t)n*256)*64;
#pragma unroll
    for (int mt = 0; mt < 4; ++mt) {
        int ocb = mt*16 + quad*4;
        float m4[4]; *(float4*)m4 = *(const float4*)&meanS[ocb];
#pragma unroll
        for (int nt = 0; nt < 4; ++nt) {
            int px = wv*64 + nt*16 + m16;
            union { f16 h[4]; uint2 u2; } ov;
#pragma unroll
            for (int r = 0; r < 4; ++r)
                ov.h[r] = (f16)(acc[mt][nt][r] - m4[r]);
            *(uint2*)(qp + (size_t)px*64 + ocb) = ov.u2;
        }
    }
}

// ---------------------------------------------------------------------------
// K5: fused bidirectional attention, no S-buffer, serial two-pass (the best
// measured structure = attn3) with two targeted fixes:
//  (1) phase-1 row stats: per-thread ONLINE (m,s) across jc, single 4-step
//      lane merge at the end  (shfl count 256 -> 64, chains 8-deep -> 4-deep)
//  (2) phase-3: P computed at scatter from hoisted rm/ri registers; raw S
//      written to a second LDS buffer for the Bv term -> the readback-exp-
//      writeback row pass and its barrier are GONE (3 -> 2 barriers/chunk).
//      Data path is bit-identical to attn3 (same f16 rounding points).
// LDS: Pl 20.8K + Sr 20.5K + Xl 5K + stats 4K = 50.5 KiB -> 3 blocks/CU.
// ---------------------------------------------------------------------------
__device__ __forceinline__ void attn_pass5(
    const f16* __restrict__ Ap, const f16* __restrict__ Bp, char* pool,
    const float* __restrict__ myM, const float* __restrict__ myI,  // by row
    const float* __restrict__ oM,  const float* __restrict__ oI,   // by col
    const float* __restrict__ xB, const float* __restrict__ xP,
    float* __restrict__ outp, int b, int h, int t)
{
    f16 (*Pl)[40] = (f16(*)[40])pool;                 // P, rows +2 (pad)
    f16 (*Sr)[40] = (f16(*)[40])(pool + 20800);       // raw S, rows 0..255
    f16 (*Xl)[40] = (f16(*)[40])(pool + 41280);
    float* scr = (float*)(pool + 41280);              // overlays Xl post-loop
    float* Vv  = (float*)(pool + 43328);
    int lane = t & 63, wv = t >> 6;
    int m16 = lane & 15, quad = lane >> 4;
    int W = wv * 32;
    int r = t & 255, hc = t >> 8;
    int cbase = hc * 16;
    int xc = t >> 3, xj = (t & 7) * 4;
    const float* xg = xB + ((size_t)(b*64 + xc)*128 + h)*256;
    // A fragments for this wave's 32 rows (constant across chunks)
    half8 af[2][2];
#pragma unroll
    for (int mt = 0; mt < 2; ++mt)
#pragma unroll
        for (int kk = 0; kk < 2; ++kk)
            af[mt][kk] = *(const half8*)(Ap + (size_t)(W + mt*16 + m16)*64 + kk*32 + quad*8);
    // hoisted per-fragment-row softmax stats (8 rows per thread)
    float rmv[8], riv[8];
#pragma unroll
    for (int mt = 0; mt < 2; ++mt)
#pragma unroll
        for (int rr = 0; rr < 4; ++rr) {
            int row = W + mt*16 + quad*4 + rr;
            rmv[mt*4 + rr] = myM[row];
            riv[mt*4 + rr] = myI[row];
        }
    f32x4 acc[2][4] = {};
    float vacc = 0.f;
    for (int kc = 0; kc < 256; kc += 32) {
        // ---- recompute S slab (32 rows/wave x 32 chunk cols) ----
        half8 bf[2][2];
#pragma unroll
        for (int nt = 0; nt < 2; ++nt)
#pragma unroll
            for (int kk = 0; kk < 2; ++kk)
                bf[nt][kk] = *(const half8*)(Bp + (size_t)(kc + nt*16 + m16)*64 + kk*32 + quad*8);
        f32x4 s1[2][2] = {};
#pragma unroll
        for (int mt = 0; mt < 2; ++mt)
#pragma unroll
            for (int nt = 0; nt < 2; ++nt) {
                s1[mt][nt] = __builtin_amdgcn_mfma_f32_16x16x32_f16(af[mt][0], bf[nt][0], s1[mt][nt], 0, 0, 0);
                s1[mt][nt] = __builtin_amdgcn_mfma_f32_16x16x32_f16(af[mt][1], bf[nt][1], s1[mt][nt], 0, 0, 0);
            }
        // stage Xl chunk
        {
            float4 x4 = *(const float4*)(xg + kc + xj);
            union { f16 h[4]; uint2 v2; } px;
            px.h[0] = (f16)x4.x; px.h[1] = (f16)x4.y;
            px.h[2] = (f16)x4.z; px.h[3] = (f16)x4.w;
            *(uint2*)&Xl[xc][xj] = px.v2;
        }
        // scatter raw S + P (P computed here from hoisted stats)
#pragma unroll
        for (int mt = 0; mt < 2; ++mt)
#pragma unroll
            for (int nt = 0; nt < 2; ++nt)
#pragma unroll
                for (int rr = 0; rr < 4; ++rr) {
                    int row = W + mt*16 + quad*4 + rr;
                    int col = nt*16 + m16;
                    f16 hv = (f16)s1[mt][nt][rr];
                    Sr[row][col] = hv;
                    int ridx = mt*4 + rr;
                    Pl[row + 2][col] = (f16)(__expf((float)hv - rmv[ridx]) * riv[ridx]);
                }
        __syncthreads();
        // ---- window + V partial (raw S from Sr, P window from Pl) ----
#pragma unroll
        for (int j8 = 0; j8 < 2; ++j8) {
            const char* wb = (const char*)&Pl[r][cbase + j8*8];
            half8 w0 = *(const half8*)(wb);
            half8 w1 = *(const half8*)(wb + 80);
            half8 w2 = *(const half8*)(wb + 160);
            half8 w3 = *(const half8*)(wb + 240);
            half8 w4 = *(const half8*)(wb + 320);
            half8 win = w0 + w1 + w2 + w3 + w4;
            half8 rw = *(const half8*)&Sr[r][cbase + j8*8];
#pragma unroll
            for (int e = 0; e < 8; ++e) {
                int j = kc + cbase + j8*8 + e;
                float Bv = __expf((float)rw[e] - oM[j]) * oI[j];
                vacc = fmaf((float)win[e], Bv, vacc);
            }
        }
        // ---- PV MFMA ----
        half8 pa[2], xb_[4];
#pragma unroll
        for (int mt = 0; mt < 2; ++mt)
            pa[mt] = *(const half8*)((const char*)&Pl[W + mt*16 + m16 + 2][0] + quad*16);
#pragma unroll
        for (int nt = 0; nt < 4; ++nt)
            xb_[nt] = *(const half8*)((const char*)&Xl[nt*16 + m16][0] + quad*16);
#pragma unroll
        for (int mt = 0; mt < 2; ++mt)
#pragma unroll
            for (int nt = 0; nt < 4; ++nt)
                acc[mt][nt] = __builtin_amdgcn_mfma_f32_16x16x32_f16(pa[mt], xb_[nt], acc[mt][nt], 0, 0, 0);
        __syncthreads();
    }
    // ---- V merge + epilogue ----
    scr[hc*256 + r] = vacc;
    __syncthreads();
    if (t < 256) Vv[t] = scr[t] + scr[256 + t];
    __syncthreads();
#pragma unroll
    for (int mt = 0; mt < 2; ++mt) {
        int i0 = W + mt*16 + quad*4;
        float v4[4];
        *(float4*)v4 = *(const float4*)&Vv[i0];
        float tv[4];
#pragma unroll
        for (int rr = 0; rr < 4; ++rr) tv[rr] = tanhf(5.f*v4[rr]);
#pragma unroll
        for (int nt = 0; nt < 4; ++nt) {
            int c = nt*16 + m16;
            size_t base = (((size_t)(b*64 + c)*128 + h) << 8) + i0;
            float xp4[4]; *(float4*)xp4 = *(const float4*)&xP[base];
            float o4[4];
#pragma unroll
            for (int rr = 0; rr < 4; ++rr)
                o4[rr] = xp4[rr]*(1.f - tv[rr]) + acc[mt][nt][rr]*tv[rr];
            *(float4*)&outp[base] = *(float4*)o4;
        }
    }
}

__global__ __launch_bounds__(512, 4) void k_attn5(
    const f16* __restrict__ Q, const f16* __restrict__ K,
    const float* __restrict__ xl, const float* __restrict__ xr,
    float* __restrict__ outL, float* __restrict__ outR)
{
    __shared__ __align__(16) char pool[46400];  // Pl/Sr/Xl ∪ colM/colS ∪ scr/Vv
    __shared__ float rmS[256], riS[256], cmS[256], ciS[256];
    float* colM = (float*)pool;            // [8][256] per-wave col partial max
    float* colS = (float*)(pool + 8192);   // [8][256] per-wave col partial sum
    int n = blockIdx.x; int b = n >> 7; int h = n & 127;
    int t = threadIdx.x;
    int lane = t & 63, wv = t >> 6;
    int m16 = lane & 15, quad = lane >> 4;
    int W = wv * 32;

    // ---- phase 1: S = Q·K^T, stats only (no store) ----
    const f16* ag = Q + (size_t)n*16384;
    const f16* bg = K + (size_t)n*16384;
    half8 af1[2][2];
#pragma unroll
    for (int mt = 0; mt < 2; ++mt)
#pragma unroll
        for (int kk = 0; kk < 2; ++kk)
            af1[mt][kk] = *(const half8*)(ag + (size_t)(W + mt*16 + m16)*64 + kk*32 + quad*8);
    float rowm[8], rows_[8];
#pragma unroll
    for (int i = 0; i < 8; ++i) { rowm[i] = -1e30f; rows_[i] = 0.f; }
    for (int jc = 0; jc < 256; jc += 64) {
        half8 bf1[4][2];
#pragma unroll
        for (int nt = 0; nt < 4; ++nt)
#pragma unroll
            for (int kk = 0; kk < 2; ++kk)
                bf1[nt][kk] = *(const half8*)(bg + (size_t)(jc + nt*16 + m16)*64 + kk*32 + quad*8);
        f32x4 acc1[2][4] = {};
#pragma unroll
        for (int mt = 0; mt < 2; ++mt)
#pragma unroll
            for (int nt = 0; nt < 4; ++nt) {
                acc1[mt][nt] = __builtin_amdgcn_mfma_f32_16x16x32_f16(af1[mt][0], bf1[nt][0], acc1[mt][nt], 0, 0, 0);
                acc1[mt][nt] = __builtin_amdgcn_mfma_f32_16x16x32_f16(af1[mt][1], bf1[nt][1], acc1[mt][nt], 0, 0, 0);
            }
        // round to f16 so stats match the recomputed (rounded) S exactly
#pragma unroll
        for (int mt = 0; mt < 2; ++mt)
#pragma unroll
            for (int nt = 0; nt < 4; ++nt)
#pragma unroll
                for (int r = 0; r < 4; ++r)
                    acc1[mt][nt][r] = (float)(f16)acc1[mt][nt][r];
        // row stats: per-thread ONLINE over in-lane 4 cols (no shfl here)
#pragma unroll
        for (int mt = 0; mt < 2; ++mt)
#pragma unroll
            for (int r = 0; r < 4; ++r) {
                int idx = mt*4 + r;
                float v0 = acc1[mt][0][r], v1 = acc1[mt][1][r];
                float v2 = acc1[mt][2][r], v3 = acc1[mt][3][r];
                float lm = fmaxf(fmaxf(v0, v1), fmaxf(v2, v3));
                float nm = fmaxf(rowm[idx], lm);
                rows_[idx] = rows_[idx]*__expf(rowm[idx] - nm)
                           + __expf(v0 - nm) + __expf(v1 - nm)
                           + __expf(v2 - nm) + __expf(v3 - nm);
                rowm[idx] = nm;
            }
        // col stats: reduce over 8 in-lane rows + 4 quads -> per-wave partial
#pragma unroll
        for (int nt = 0; nt < 4; ++nt) {
            float lm = acc1[0][nt][0];
#pragma unroll
            for (int r = 1; r < 4; ++r) lm = fmaxf(lm, acc1[0][nt][r]);
#pragma unroll
            for (int r = 0; r < 4; ++r) lm = fmaxf(lm, acc1[1][nt][r]);
            lm = fmaxf(lm, __shfl_xor(lm, 16));
            lm = fmaxf(lm, __shfl_xor(lm, 32));
            float le = 0.f;
#pragma unroll
            for (int mt2 = 0; mt2 < 2; ++mt2)
#pragma unroll
                for (int r = 0; r < 4; ++r) le += __expf(acc1[mt2][nt][r] - lm);
            le += __shfl_xor(le, 16); le += __shfl_xor(le, 32);
            if (quad == 0) {
                int col = jc + nt*16 + m16;
                colM[wv*256 + col] = lm;
                colS[wv*256 + col] = le;
            }
        }
    }
    // row stats: single 4-step merge across the 16 m16-lanes
#pragma unroll
    for (int idx = 0; idx < 8; ++idx) {
        float m = rowm[idx], s = rows_[idx];
#pragma unroll
        for (int off = 1; off < 16; off <<= 1) {
            float m2 = __shfl_xor(m, off);
            float s2 = __shfl_xor(s, off);
            float nm = fmaxf(m, m2);
            s = s*__expf(m - nm) + s2*__expf(m2 - nm);
            m = nm;
        }
        rowm[idx] = m; rows_[idx] = s;
    }
    if (m16 == 0) {
#pragma unroll
        for (int mt = 0; mt < 2; ++mt)
#pragma unroll
            for (int r = 0; r < 4; ++r) {
                int row = W + mt*16 + quad*4 + r;
                rmS[row] = rowm[mt*4 + r];
                riS[row] = 1.0f / rows_[mt*4 + r];
            }
    }
    __syncthreads();
    // merge 8 per-wave col partials
    if (t < 256) {
        float m = colM[t], s = colS[t];
#pragma unroll
        for (int w = 1; w < 8; ++w) {
            float m2 = colM[w*256 + t], s2 = colS[w*256 + t];
            float nm = fmaxf(m, m2);
            s = s*__expf(m - nm) + s2*__expf(m2 - nm);
            m = nm;
        }
        cmS[t] = m; ciS[t] = 1.0f / s;
    }
    __syncthreads();
    // zero Pl window-pad rows (0,1 and 258,259) — pool now free
    if (t < 10)       *(uint4*)(pool + t*16)              = make_uint4(0,0,0,0);
    else if (t < 20)  *(uint4*)(pool + 20640 + (t-10)*16) = make_uint4(0,0,0,0);

    // ---- left pass: rows of S, stats (rm, cm), PV with x_right ----
    attn_pass5(ag, bg, pool, rmS, riS, cmS, ciS, xr, xl, outL, b, h, t);
    __syncthreads();   // protect pool reuse (Vv/Xl overlap)
    // ---- right pass: S^T recomputed directly (K·Q^T), stats swapped ----
    attn_pass5(bg, ag, pool, cmS, ciS, rmS, riS, xl, xr, outR, b, h, t);
}

// ---------------------------------------------------------------------------
extern "C" void kernel_launch(void* const* d_in, const int* in_sizes, int n_in,
                              void* d_out, int out_size, void* d_ws, size_t ws_size,
                              hipStream_t stream)
{
    const float* x_left  = (const float*)d_in[0];
    const float* x_right = (const float*)d_in[1];
    const float* conv1_w = (const float*)d_in[2];
    const float* conv1_b = (const float*)d_in[3];
    const float* conv2_w = (const float*)d_in[4];
    const float* conv2_b = (const float*)d_in[5];
    const float* bn_g    = (const float*)d_in[6];
    const float* bn_b    = (const float*)d_in[7];
    const float* bn_m    = (const float*)d_in[8];
    const float* bn_v    = (const float*)d_in[9];
    const float* rb_w1   = (const float*)d_in[10];
    const float* rb_b1   = (const float*)d_in[11];
    const float* rb_w2   = (const float*)d_in[12];
    const float* rb_b2   = (const float*)d_in[13];
    const float* bq_w    = (const float*)d_in[14];
    const float* bs_w    = (const float*)d_in[16];

    f16* W16 = (f16*)d_ws;
    f16* u  = W16;                       // 16,777,216 els
    f16* y1 = W16 + 16777216;            // 16,777,216
    f16* r  = W16 + 33554432;            // 16,777,216
    f16* Qh = W16 + 67108864;            //  8,388,608
    f16* Kh = W16 + 75497472;            //  8,388,608
    f16* Wp1 = W16 + 84934656;           // 36,864 els (prepped rb_w1)
    f16* Wp2 = W16 + 84971520;           // 36,864 els (prepped rb_w2)

    float* out_left  = (float*)d_out;
    float* out_right = (float*)d_out + 8388608;

    // ---- weight prep (once per launch) ----
    k_wprep<<<dim3(4, 2), 256, 0, stream>>>(rb_w1, rb_w2, Wp1, Wp2);

    // ---- left branch -> Q ----
    k_catbn_m<<<NN, 256, 0, stream>>>(x_left, conv1_w, conv1_b, bn_g, bn_b, bn_m, bn_v, u);
    k_conv3r<true,  false><<<dim3(256, 4, 2), 256, 0, stream>>>(u, Wp1, rb_b1, nullptr, y1);
    k_conv3r<false, true ><<<dim3(256, 4, 2), 256, 0, stream>>>(y1, Wp2, rb_b2, u, r);
    k_conv1x1m<<<NN, 256, 0, stream>>>(r, bq_w, Qh);

    // ---- right branch -> K ----
    k_catbn_m<<<NN, 256, 0, stream>>>(x_right, conv2_w, conv2_b, bn_g, bn_b, bn_m, bn_v, u);
    k_conv3r<true,  false><<<dim3(256, 4, 2), 256, 0, stream>>>(u, Wp1, rb_b1, nullptr, y1);
    k_conv3r<false, true ><<<dim3(256, 4, 2), 256, 0, stream>>>(y1, Wp2, rb_b2, u, r);
    k_conv1x1m<<<NN, 256, 0, stream>>>(r, bs_w, Kh);

    // ---- fused attention tail (serial two-pass, 2-barrier chunks) ----
    k_attn5<<<NN, 512, 0, stream>>>(Qh, Kh, x_left, x_right, out_left, out_right);
}

// Round 11
// 459.741 us; speedup vs baseline: 1.6070x; 1.0236x over previous
//
#include <hip/hip_runtime.h>
#include <math.h>

// Problem constants
#define BB 4
#define CC 64
#define C2 128
#define HH 128
#define WW 256
#define NN (BB*HH)          // 512 row-pairs
#define EPSBN 1e-5f
#define BROFF 16777216ull   // per-branch offset for u/y1 (f16 els)

typedef _Float16 f16;
typedef _Float16 half8 __attribute__((ext_vector_type(8)));
typedef float f32x4 __attribute__((ext_vector_type(4)));

// ---------------------------------------------------------------------------
// K0: weight prep — rb_w fp32 [o][icg][3][3] -> f16 [g][mo][ks*32+ic]
// ---------------------------------------------------------------------------
__global__ __launch_bounds__(256) void k_wprep(
    const float* __restrict__ w1, const float* __restrict__ w2,
    f16* __restrict__ wp1, f16* __restrict__ wp2)
{
    int g = blockIdx.x; int which = blockIdx.y;
    const float* src = which ? w2 : w1;
    f16* dst = which ? wp2 : wp1;
    for (int p = threadIdx.x; p < 9216; p += 256) {
        int mo = p / 288; int kr = p - mo*288;
        int ks = kr >> 5; int ic = kr & 31;
        dst[g*9216 + p] = (f16)src[((g*32 + mo)*32 + ic)*9 + ks];
    }
}

// ---------------------------------------------------------------------------
// K1: fused 1x1 conv (64->64) + concat + batchnorm -> u (channel-last f16)
// MERGED: grid (512, 2) — blockIdx.y selects the branch (left/right).
// ---------------------------------------------------------------------------
__global__ __launch_bounds__(256) void k_catbn_m(
    const float* __restrict__ x_l, const float* __restrict__ x_r,
    const float* __restrict__ cw1, const float* __restrict__ cw2,
    const float* __restrict__ cb1, const float* __restrict__ cb2,
    const float* __restrict__ g, const float* __restrict__ bb_, const float* __restrict__ m,
    const float* __restrict__ v, f16* __restrict__ u)
{
    __shared__ f16 Xl[256][72];   // [px][ic]
    __shared__ f16 Wl[64][72];    // [oc][ic]
    __shared__ float sS[64], sT[64], sS2[64], sT2[64];
    int n = blockIdx.x; int br = blockIdx.y;
    int b = n >> 7; int h = n & 127; int t = threadIdx.x;
    const float* x  = br ? x_r : x_l;
    const float* cw = br ? cw2 : cw1;
    const float* cb = br ? cb2 : cb1;
    f16* ub = u + (size_t)br * BROFF;
    for (int p = t; p < 2048; p += 256) {
        int idx = p * 2; int o = idx >> 6, i = idx & 63;
        union { f16 h[2]; unsigned int u1; } pr;
        pr.h[0] = (f16)cw[idx]; pr.h[1] = (f16)cw[idx + 1];
        *(unsigned int*)&Wl[o][i] = pr.u1;
    }
    if (t < 64) {
        float inv = rsqrtf(v[t] + EPSBN); float s = g[t] * inv;
        sS[t] = s; sT[t] = bb_[t] + s * (cb[t] - m[t]);
        float inv2 = rsqrtf(v[t + 64] + EPSBN); float s2 = g[t + 64] * inv2;
        sS2[t] = s2; sT2[t] = bb_[t + 64] - s2 * m[t + 64];
    }
    __syncthreads();
    f16* up = ub + ((size_t)(n*256 + t)) * 128;
    for (int c8 = 0; c8 < 8; ++c8) {
        float xv8[8];
#pragma unroll
        for (int j = 0; j < 8; ++j)
            xv8[j] = x[(((b*64 + c8*8 + j)*128 + h) << 8) + t];
        union { f16 h[8]; uint4 v4; } pk;
#pragma unroll
        for (int j = 0; j < 8; ++j) {
            int c = c8*8 + j;
            pk.h[j] = (f16)(sS2[c]*xv8[j] + sT2[c]);
        }
        *(uint4*)(up + 64 + c8*8) = pk.v4;
#pragma unroll
        for (int j2 = 0; j2 < 4; ++j2) {
            union { f16 h[2]; unsigned int u1; } q;
            q.h[0] = (f16)xv8[j2*2]; q.h[1] = (f16)xv8[j2*2 + 1];
            *(unsigned int*)&Xl[t][c8*8 + j2*2] = q.u1;
        }
    }
    __syncthreads();
    int lane = t & 63, wv = t >> 6;
    int m16 = lane & 15, quad = lane >> 4;
    half8 af[4][2], bf[4][2];
#pragma unroll
    for (int mt = 0; mt < 4; ++mt)
#pragma unroll
        for (int kk = 0; kk < 2; ++kk)
            af[mt][kk] = *(const half8*)&Wl[mt*16 + m16][kk*32 + quad*8];
#pragma unroll
    for (int nt = 0; nt < 4; ++nt)
#pragma unroll
        for (int kk = 0; kk < 2; ++kk)
            bf[nt][kk] = *(const half8*)&Xl[wv*64 + nt*16 + m16][kk*32 + quad*8];
    f32x4 acc[4][4] = {};
#pragma unroll
    for (int mt = 0; mt < 4; ++mt)
#pragma unroll
        for (int nt = 0; nt < 4; ++nt) {
            acc[mt][nt] = __builtin_amdgcn_mfma_f32_16x16x32_f16(af[mt][0], bf[nt][0], acc[mt][nt], 0, 0, 0);
            acc[mt][nt] = __builtin_amdgcn_mfma_f32_16x16x32_f16(af[mt][1], bf[nt][1], acc[mt][nt], 0, 0, 0);
        }
#pragma unroll
    for (int mt = 0; mt < 4; ++mt) {
        int ocb = mt*16 + quad*4;
        float s4[4], t4[4];
        *(float4*)s4 = *(const float4*)&sS[ocb];
        *(float4*)t4 = *(const float4*)&sT[ocb];
#pragma unroll
        for (int nt = 0; nt < 4; ++nt) {
            int px = wv*64 + nt*16 + m16;
            union { f16 h[4]; uint2 u2; } ov;
#pragma unroll
            for (int r = 0; r < 4; ++r)
                ov.h[r] = (f16)(s4[r]*acc[mt][nt][r] + t4[r]);
            *(uint2*)(ub + ((size_t)(n*256 + px))*128 + ocb) = ov.u2;
        }
    }
}

// ---------------------------------------------------------------------------
// K2/K3: grouped 3x3 conv, implicit-GEMM f16 MFMA.
// MERGED: grid (256, 4, 4) — z = wtile + 2*branch; both branches share
// weights.  RES variant reads the residual from the OUTPUT pointer itself
// (element-wise, per-block-exclusive rows -> in-place u += conv is safe).
// 2 output rows per block (4 staged rows, 41.6 KB LDS) -> 3 blocks/CU.
// ---------------------------------------------------------------------------
template<bool LEAKY, bool RES>
__global__ __launch_bounds__(256, 3) void k_conv3r(
    const f16* __restrict__ inB, const f16* __restrict__ wp,
    const float* __restrict__ bias, f16* __restrict__ outB)
{
    __shared__ f16 Xl[4*130*40];  // [row][px][ic] px-stride 40
    int b = blockIdx.x >> 6; int h0 = (blockIdx.x & 63) * 2;
    int g = blockIdx.y;
    int wt = blockIdx.z & 1; int branch = blockIdx.z >> 1;
    int w0 = wt * 128;
    const f16* in = inB + (size_t)branch * BROFF;
    f16* out = outB + (size_t)branch * BROFF;
    int t = threadIdx.x;
    int lane = t & 63, wv = t >> 6;
    int m16 = lane & 15, quad = lane >> 4;
    const f16* wg = wp + g*9216;
    half8 af[2][9];
#pragma unroll
    for (int mt = 0; mt < 2; ++mt)
#pragma unroll
        for (int ks = 0; ks < 9; ++ks)
            af[mt][ks] = *(const half8*)(wg + (mt*16 + m16)*288 + ks*32 + quad*8);
    float bo[2][4];
#pragma unroll
    for (int mt = 0; mt < 2; ++mt)
#pragma unroll
        for (int r = 0; r < 4; ++r)
            bo[mt][r] = bias[g*32 + mt*16 + quad*4 + r];
    // ---- stage 4 input rows (h0-1 .. h0+2) ----
    for (int idx = t; idx < 2080; idx += 256) {
        int r = idx / 520; int rem = idx - r*520; int p = rem >> 2; int q = rem & 3;
        int hr = h0 + r - 1; int wg2 = w0 + p - 1;
        uint4 val = make_uint4(0,0,0,0);
        if ((unsigned)wg2 < 256u && (unsigned)hr < 128u)
            val = *(const uint4*)(in + ((size_t)((b*128 + hr)*256 + wg2))*128 + g*32 + q*8);
        *(uint4*)&Xl[(r*130 + p)*40 + q*8] = val;
    }
    __syncthreads();
    int px0 = wv*32 + m16;
#pragma unroll
    for (int rr = 0; rr < 2; ++rr) {
        f32x4 acc[2][2] = {};
#pragma unroll
        for (int ks = 0; ks < 9; ++ks) {
            int ky = ks / 3, kx = ks - ky*3;
            half8 bf0 = *(const half8*)&Xl[((rr + ky)*130 + px0 + kx)*40 + quad*8];
            half8 bf1 = *(const half8*)&Xl[((rr + ky)*130 + px0 + 16 + kx)*40 + quad*8];
            acc[0][0] = __builtin_amdgcn_mfma_f32_16x16x32_f16(af[0][ks], bf0, acc[0][0], 0, 0, 0);
            acc[0][1] = __builtin_amdgcn_mfma_f32_16x16x32_f16(af[0][ks], bf1, acc[0][1], 0, 0, 0);
            acc[1][0] = __builtin_amdgcn_mfma_f32_16x16x32_f16(af[1][ks], bf0, acc[1][0], 0, 0, 0);
            acc[1][1] = __builtin_amdgcn_mfma_f32_16x16x32_f16(af[1][ks], bf1, acc[1][1], 0, 0, 0);
        }
        int h = h0 + rr;
#pragma unroll
        for (int mt = 0; mt < 2; ++mt)
#pragma unroll
            for (int nt = 0; nt < 2; ++nt) {
                int px = w0 + wv*32 + nt*16 + m16;
                int oc = g*32 + mt*16 + quad*4;
                size_t off = ((size_t)((b*128 + h)*256 + px))*128 + oc;
                float rv4[4] = {0.f, 0.f, 0.f, 0.f};
                if (RES) {
                    union { f16 h[4]; uint2 v2; } rrd;
                    rrd.v2 = *(const uint2*)(out + off);   // in-place residual
#pragma unroll
                    for (int r = 0; r < 4; ++r) rv4[r] = (float)rrd.h[r];
                }
                union { f16 h[4]; uint2 v2; } ov;
#pragma unroll
                for (int r = 0; r < 4; ++r) {
                    float y = acc[mt][nt][r] + bo[mt][r];
                    if (LEAKY) y = y > 0.f ? y : 0.1f*y;
                    if (RES) y += rv4[r];
                    ov.h[r] = (f16)y;
                }
                *(uint2*)(out + off) = ov.v2;
            }
    }
}

// ---------------------------------------------------------------------------
// K4: grouped 1x1 conv (128->64, groups=2) + row-mean subtraction, MFMA f16.
// MERGED: grid (512, 2) — blockIdx.y selects branch (weights + output).
// ---------------------------------------------------------------------------
__global__ __launch_bounds__(256, 2) void k_conv1x1m(
    const f16* __restrict__ inB, const float* __restrict__ wq,
    const float* __restrict__ ws, f16* __restrict__ outq)
{
    __shared__ f16 Xl[256][72];       // one group's 64 ic (+8 pad)
    __shared__ f16 Wl[64][72];        // all 64 oc, within-group ic
    __shared__ float partial[4][64];  // per-wave px-sums per oc
    __shared__ float meanS[64];
    int n = blockIdx.x; int br = blockIdx.y; int t = threadIdx.x;
    const float* wgt = br ? ws : wq;
    const f16* in = inB + (size_t)br * BROFF;
    f16* outb = outq + (size_t)br * 8388608ull;
    int lane = t & 63, wv = t >> 6;
    int m16 = lane & 15, quad = lane >> 4;
    for (int p = t; p < 2048; p += 256) {
        int idx = p * 2; int o = idx >> 6, i = idx & 63;
        union { f16 h[2]; unsigned int u1; } pr;
        pr.h[0] = (f16)wgt[idx]; pr.h[1] = (f16)wgt[idx + 1];
        *(unsigned int*)&Wl[o][i] = pr.u1;
    }
    f32x4 acc[4][4] = {};             // [oc tile 0..3][px tile 0..3]
    const f16* rp = in + ((size_t)n*256 + t)*128;
    for (int g = 0; g < 2; ++g) {
#pragma unroll
        for (int i8 = 0; i8 < 8; ++i8)
            *(uint4*)&Xl[t][i8*8] = *(const uint4*)(rp + g*64 + i8*8);
        __syncthreads();
        half8 af[2][2], bf[4][2];
#pragma unroll
        for (int ml = 0; ml < 2; ++ml)
#pragma unroll
            for (int kk = 0; kk < 2; ++kk)
                af[ml][kk] = *(const half8*)&Wl[g*32 + ml*16 + m16][kk*32 + quad*8];
#pragma unroll
        for (int nt = 0; nt < 4; ++nt)
#pragma unroll
            for (int kk = 0; kk < 2; ++kk)
                bf[nt][kk] = *(const half8*)&Xl[wv*64 + nt*16 + m16][kk*32 + quad*8];
#pragma unroll
        for (int ml = 0; ml < 2; ++ml)
#pragma unroll
            for (int nt = 0; nt < 4; ++nt) {
                int mt = g*2 + ml;
                acc[mt][nt] = __builtin_amdgcn_mfma_f32_16x16x32_f16(af[ml][0], bf[nt][0], acc[mt][nt], 0, 0, 0);
                acc[mt][nt] = __builtin_amdgcn_mfma_f32_16x16x32_f16(af[ml][1], bf[nt][1], acc[mt][nt], 0, 0, 0);
            }
        __syncthreads();
    }
#pragma unroll
    for (int mt = 0; mt < 4; ++mt)
#pragma unroll
        for (int r = 0; r < 4; ++r) {
            float s = acc[mt][0][r] + acc[mt][1][r] + acc[mt][2][r] + acc[mt][3][r];
            s += __shfl_xor(s, 1); s += __shfl_xor(s, 2);
            s += __shfl_xor(s, 4); s += __shfl_xor(s, 8);
            if (m16 == 0) partial[wv][mt*16 + quad*4 + r] = s;
        }
    __syncthreads();
    if (t < 64)
        meanS[t] = (partial[0][t] + partial[1][t] + partial[2][t] + partial[3][t]) * (1.0f/256.0f);
    __syncthreads();
    f16* qp = outb + ((size_t)n*256)*64;
#pragma unroll
    for (int mt = 0; mt < 4; ++mt) {
        int ocb = mt*16 + quad*4;
        float m4[4]; *(float4*)m4 = *(const float4*)&meanS[ocb];
#pragma unroll
        for (int nt = 0; nt < 4; ++nt) {
            int px = wv*64 + nt*16 + m16;
            union { f16 h[4]; uint2 u2; } ov;
#pragma unroll
            for (int r = 0; r < 4; ++r)
                ov.h[r] = (f16)(acc[mt][nt][r] - m4[r]);
            *(uint2*)(qp + (size_t)px*64 + ocb) = ov.u2;
        }
    }
}

// ---------------------------------------------------------------------------
// K5: fused bidirectional attention (R10 attn5, unchanged).
// LDS: Pl 20.8K + Sr 20.5K + Xl 5K + stats 4K = 50.5 KiB -> 3 blocks/CU.
// ---------------------------------------------------------------------------
__device__ __forceinline__ void attn_pass5(
    const f16* __restrict__ Ap, const f16* __restrict__ Bp, char* pool,
    const float* __restrict__ myM, const float* __restrict__ myI,  // by row
    const float* __restrict__ oM,  const float* __restrict__ oI,   // by col
    const float* __restrict__ xB, const float* __restrict__ xP,
    float* __restrict__ outp, int b, int h, int t)
{
    f16 (*Pl)[40] = (f16(*)[40])pool;                 // P, rows +2 (pad)
    f16 (*Sr)[40] = (f16(*)[40])(pool + 20800);       // raw S, rows 0..255
    f16 (*Xl)[40] = (f16(*)[40])(pool + 41280);
    float* scr = (float*)(pool + 41280);              // overlays Xl post-loop
    float* Vv  = (float*)(pool + 43328);
    int lane = t & 63, wv = t >> 6;
    int m16 = lane & 15, quad = lane >> 4;
    int W = wv * 32;
    int r = t & 255, hc = t >> 8;
    int cbase = hc * 16;
    int xc = t >> 3, xj = (t & 7) * 4;
    const float* xg = xB + ((size_t)(b*64 + xc)*128 + h)*256;
    half8 af[2][2];
#pragma unroll
    for (int mt = 0; mt < 2; ++mt)
#pragma unroll
        for (int kk = 0; kk < 2; ++kk)
            af[mt][kk] = *(const half8*)(Ap + (size_t)(W + mt*16 + m16)*64 + kk*32 + quad*8);
    float rmv[8], riv[8];
#pragma unroll
    for (int mt = 0; mt < 2; ++mt)
#pragma unroll
        for (int rr = 0; rr < 4; ++rr) {
            int row = W + mt*16 + quad*4 + rr;
            rmv[mt*4 + rr] = myM[row];
            riv[mt*4 + rr] = myI[row];
        }
    f32x4 acc[2][4] = {};
    float vacc = 0.f;
    for (int kc = 0; kc < 256; kc += 32) {
        half8 bf[2][2];
#pragma unroll
        for (int nt = 0; nt < 2; ++nt)
#pragma unroll
            for (int kk = 0; kk < 2; ++kk)
                bf[nt][kk] = *(const half8*)(Bp + (size_t)(kc + nt*16 + m16)*64 + kk*32 + quad*8);
        f32x4 s1[2][2] = {};
#pragma unroll
        for (int mt = 0; mt < 2; ++mt)
#pragma unroll
            for (int nt = 0; nt < 2; ++nt) {
                s1[mt][nt] = __builtin_amdgcn_mfma_f32_16x16x32_f16(af[mt][0], bf[nt][0], s1[mt][nt], 0, 0, 0);
                s1[mt][nt] = __builtin_amdgcn_mfma_f32_16x16x32_f16(af[mt][1], bf[nt][1], s1[mt][nt], 0, 0, 0);
            }
        {
            float4 x4 = *(const float4*)(xg + kc + xj);
            union { f16 h[4]; uint2 v2; } px;
            px.h[0] = (f16)x4.x; px.h[1] = (f16)x4.y;
            px.h[2] = (f16)x4.z; px.h[3] = (f16)x4.w;
            *(uint2*)&Xl[xc][xj] = px.v2;
        }
#pragma unroll
        for (int mt = 0; mt < 2; ++mt)
#pragma unroll
            for (int nt = 0; nt < 2; ++nt)
#pragma unroll
                for (int rr = 0; rr < 4; ++rr) {
                    int row = W + mt*16 + quad*4 + rr;
                    int col = nt*16 + m16;
                    f16 hv = (f16)s1[mt][nt][rr];
                    Sr[row][col] = hv;
                    int ridx = mt*4 + rr;
                    Pl[row + 2][col] = (f16)(__expf((float)hv - rmv[ridx]) * riv[ridx]);
                }
        __syncthreads();
#pragma unroll
        for (int j8 = 0; j8 < 2; ++j8) {
            const char* wb = (const char*)&Pl[r][cbase + j8*8];
            half8 w0 = *(const half8*)(wb);
            half8 w1 = *(const half8*)(wb + 80);
            half8 w2 = *(const half8*)(wb + 160);
            half8 w3 = *(const half8*)(wb + 240);
            half8 w4 = *(const half8*)(wb + 320);
            half8 win = w0 + w1 + w2 + w3 + w4;
            half8 rw = *(const half8*)&Sr[r][cbase + j8*8];
#pragma unroll
            for (int e = 0; e < 8; ++e) {
                int j = kc + cbase + j8*8 + e;
                float Bv = __expf((float)rw[e] - oM[j]) * oI[j];
                vacc = fmaf((float)win[e], Bv, vacc);
            }
        }
        half8 pa[2], xb_[4];
#pragma unroll
        for (int mt = 0; mt < 2; ++mt)
            pa[mt] = *(const half8*)((const char*)&Pl[W + mt*16 + m16 + 2][0] + quad*16);
#pragma unroll
        for (int nt = 0; nt < 4; ++nt)
            xb_[nt] = *(const half8*)((const char*)&Xl[nt*16 + m16][0] + quad*16);
#pragma unroll
        for (int mt = 0; mt < 2; ++mt)
#pragma unroll
            for (int nt = 0; nt < 4; ++nt)
                acc[mt][nt] = __builtin_amdgcn_mfma_f32_16x16x32_f16(pa[mt], xb_[nt], acc[mt][nt], 0, 0, 0);
        __syncthreads();
    }
    scr[hc*256 + r] = vacc;
    __syncthreads();
    if (t < 256) Vv[t] = scr[t] + scr[256 + t];
    __syncthreads();
#pragma unroll
    for (int mt = 0; mt < 2; ++mt) {
        int i0 = W + mt*16 + quad*4;
        float v4[4];
        *(float4*)v4 = *(const float4*)&Vv[i0];
        float tv[4];
#pragma unroll
        for (int rr = 0; rr < 4; ++rr) tv[rr] = tanhf(5.f*v4[rr]);
#pragma unroll
        for (int nt = 0; nt < 4; ++nt) {
            int c = nt*16 + m16;
            size_t base = (((size_t)(b*64 + c)*128 + h) << 8) + i0;
            float xp4[4]; *(float4*)xp4 = *(const float4*)&xP[base];
            float o4[4];
#pragma unroll
            for (int rr = 0; rr < 4; ++rr)
                o4[rr] = xp4[rr]*(1.f - tv[rr]) + acc[mt][nt][rr]*tv[rr];
            *(float4*)&outp[base] = *(float4*)o4;
        }
    }
}

__global__ __launch_bounds__(512, 4) void k_attn5(
    const f16* __restrict__ Q, const f16* __restrict__ K,
    const float* __restrict__ xl, const float* __restrict__ xr,
    float* __restrict__ outL, float* __restrict__ outR)
{
    __shared__ __align__(16) char pool[46400];  // Pl/Sr/Xl ∪ colM/colS ∪ scr/Vv
    __shared__ float rmS[256], riS[256], cmS[256], ciS[256];
    float* colM = (float*)pool;            // [8][256] per-wave col partial max
    float* colS = (float*)(pool + 8192);   // [8][256] per-wave col partial sum
    int n = blockIdx.x; int b = n >> 7; int h = n & 127;
    int t = threadIdx.x;
    int lane = t & 63, wv = t >> 6;
    int m16 = lane & 15, quad = lane >> 4;
    int W = wv * 32;

    // ---- phase 1: S = Q·K^T, stats only (no store) ----
    const f16* ag = Q + (size_t)n*16384;
    const f16* bg = K + (size_t)n*16384;
    half8 af1[2][2];
#pragma unroll
    for (int mt = 0; mt < 2; ++mt)
#pragma unroll
        for (int kk = 0; kk < 2; ++kk)
            af1[mt][kk] = *(const half8*)(ag + (size_t)(W + mt*16 + m16)*64 + kk*32 + quad*8);
    float rowm[8], rows_[8];
#pragma unroll
    for (int i = 0; i < 8; ++i) { rowm[i] = -1e30f; rows_[i] = 0.f; }
    for (int jc = 0; jc < 256; jc += 64) {
        half8 bf1[4][2];
#pragma unroll
        for (int nt = 0; nt < 4; ++nt)
#pragma unroll
            for (int kk = 0; kk < 2; ++kk)
                bf1[nt][kk] = *(const half8*)(bg + (size_t)(jc + nt*16 + m16)*64 + kk*32 + quad*8);
        f32x4 acc1[2][4] = {};
#pragma unroll
        for (int mt = 0; mt < 2; ++mt)
#pragma unroll
            for (int nt = 0; nt < 4; ++nt) {
                acc1[mt][nt] = __builtin_amdgcn_mfma_f32_16x16x32_f16(af1[mt][0], bf1[nt][0], acc1[mt][nt], 0, 0, 0);
                acc1[mt][nt] = __builtin_amdgcn_mfma_f32_16x16x32_f16(af1[mt][1], bf1[nt][1], acc1[mt][nt], 0, 0, 0);
            }
#pragma unroll
        for (int mt = 0; mt < 2; ++mt)
#pragma unroll
            for (int nt = 0; nt < 4; ++nt)
#pragma unroll
                for (int r = 0; r < 4; ++r)
                    acc1[mt][nt][r] = (float)(f16)acc1[mt][nt][r];
        // row stats: per-thread ONLINE over in-lane 4 cols (no shfl here)
#pragma unroll
        for (int mt = 0; mt < 2; ++mt)
#pragma unroll
            for (int r = 0; r < 4; ++r) {
                int idx = mt*4 + r;
                float v0 = acc1[mt][0][r], v1 = acc1[mt][1][r];
                float v2 = acc1[mt][2][r], v3 = acc1[mt][3][r];
                float lm = fmaxf(fmaxf(v0, v1), fmaxf(v2, v3));
                float nm = fmaxf(rowm[idx], lm);
                rows_[idx] = rows_[idx]*__expf(rowm[idx] - nm)
                           + __expf(v0 - nm) + __expf(v1 - nm)
                           + __expf(v2 - nm) + __expf(v3 - nm);
                rowm[idx] = nm;
            }
        // col stats: reduce over 8 in-lane rows + 4 quads -> per-wave partial
#pragma unroll
        for (int nt = 0; nt < 4; ++nt) {
            float lm = acc1[0][nt][0];
#pragma unroll
            for (int r = 1; r < 4; ++r) lm = fmaxf(lm, acc1[0][nt][r]);
#pragma unroll
            for (int r = 0; r < 4; ++r) lm = fmaxf(lm, acc1[1][nt][r]);
            lm = fmaxf(lm, __shfl_xor(lm, 16));
            lm = fmaxf(lm, __shfl_xor(lm, 32));
            float le = 0.f;
#pragma unroll
            for (int mt2 = 0; mt2 < 2; ++mt2)
#pragma unroll
                for (int r = 0; r < 4; ++r) le += __expf(acc1[mt2][nt][r] - lm);
            le += __shfl_xor(le, 16); le += __shfl_xor(le, 32);
            if (quad == 0) {
                int col = jc + nt*16 + m16;
                colM[wv*256 + col] = lm;
                colS[wv*256 + col] = le;
            }
        }
    }
    // row stats: single 4-step merge across the 16 m16-lanes
#pragma unroll
    for (int idx = 0; idx < 8; ++idx) {
        float m = rowm[idx], s = rows_[idx];
#pragma unroll
        for (int off = 1; off < 16; off <<= 1) {
            float m2 = __shfl_xor(m, off);
            float s2 = __shfl_xor(s, off);
            float nm = fmaxf(m, m2);
            s = s*__expf(m - nm) + s2*__expf(m2 - nm);
            m = nm;
        }
        rowm[idx] = m; rows_[idx] = s;
    }
    if (m16 == 0) {
#pragma unroll
        for (int mt = 0; mt < 2; ++mt)
#pragma unroll
            for (int r = 0; r < 4; ++r) {
                int row = W + mt*16 + quad*4 + r;
                rmS[row] = rowm[mt*4 + r];
                riS[row] = 1.0f / rows_[mt*4 + r];
            }
    }
    __syncthreads();
    if (t < 256) {
        float m = colM[t], s = colS[t];
#pragma unroll
        for (int w = 1; w < 8; ++w) {
            float m2 = colM[w*256 + t], s2 = colS[w*256 + t];
            float nm = fmaxf(m, m2);
            s = s*__expf(m - nm) + s2*__expf(m2 - nm);
            m = nm;
        }
        cmS[t] = m; ciS[t] = 1.0f / s;
    }
    __syncthreads();
    if (t < 10)       *(uint4*)(pool + t*16)              = make_uint4(0,0,0,0);
    else if (t < 20)  *(uint4*)(pool + 20640 + (t-10)*16) = make_uint4(0,0,0,0);

    attn_pass5(ag, bg, pool, rmS, riS, cmS, ciS, xr, xl, outL, b, h, t);
    __syncthreads();
    attn_pass5(bg, ag, pool, cmS, ciS, rmS, riS, xl, xr, outR, b, h, t);
}

// ---------------------------------------------------------------------------
extern "C" void kernel_launch(void* const* d_in, const int* in_sizes, int n_in,
                              void* d_out, int out_size, void* d_ws, size_t ws_size,
                              hipStream_t stream)
{
    const float* x_left  = (const float*)d_in[0];
    const float* x_right = (const float*)d_in[1];
    const float* conv1_w = (const float*)d_in[2];
    const float* conv1_b = (const float*)d_in[3];
    const float* conv2_w = (const float*)d_in[4];
    const float* conv2_b = (const float*)d_in[5];
    const float* bn_g    = (const float*)d_in[6];
    const float* bn_b    = (const float*)d_in[7];
    const float* bn_m    = (const float*)d_in[8];
    const float* bn_v    = (const float*)d_in[9];
    const float* rb_w1   = (const float*)d_in[10];
    const float* rb_b1   = (const float*)d_in[11];
    const float* rb_w2   = (const float*)d_in[12];
    const float* rb_b2   = (const float*)d_in[13];
    const float* bq_w    = (const float*)d_in[14];
    const float* bs_w    = (const float*)d_in[16];

    // Workspace layout (f16 els) — max 83,959,808 < 85.0M known-good (R0):
    //   u   [2 branches] : 0        .. 33,554,432   (becomes r in-place)
    //   y1  [2 branches] : 33,554,432 .. 67,108,864
    //   Qh               : 67,108,864 (8,388,608);  Kh = Qh + 8,388,608
    //   Wp1/Wp2          : 83,886,080 .. +73,728
    f16* W16 = (f16*)d_ws;
    f16* u   = W16;
    f16* y1  = W16 + 33554432;
    f16* Qh  = W16 + 67108864;
    f16* Kh  = W16 + 75497472;
    f16* Wp1 = W16 + 83886080;
    f16* Wp2 = W16 + 83886080 + 36864;

    float* out_left  = (float*)d_out;
    float* out_right = (float*)d_out + 8388608;

    // ---- weight prep ----
    k_wprep<<<dim3(4, 2), 256, 0, stream>>>(rb_w1, rb_w2, Wp1, Wp2);

    // ---- both branches, merged dispatches ----
    k_catbn_m<<<dim3(NN, 2), 256, 0, stream>>>(
        x_left, x_right, conv1_w, conv2_w, conv1_b, conv2_b,
        bn_g, bn_b, bn_m, bn_v, u);
    k_conv3r<true,  false><<<dim3(256, 4, 4), 256, 0, stream>>>(u,  Wp1, rb_b1, y1);
    k_conv3r<false, true ><<<dim3(256, 4, 4), 256, 0, stream>>>(y1, Wp2, rb_b2, u);  // r -> u in-place
    k_conv1x1m<<<dim3(NN, 2), 256, 0, stream>>>(u, bq_w, bs_w, Qh);

    // ---- fused attention tail ----
    k_attn5<<<NN, 512, 0, stream>>>(Qh, Kh, x_left, x_right, out_left, out_right);
}

// Round 12
// 443.952 us; speedup vs baseline: 1.6641x; 1.0356x over previous
//
#include <hip/hip_runtime.h>
#include <math.h>

// Problem constants
#define BB 4
#define CC 64
#define C2 128
#define HH 128
#define WW 256
#define NN (BB*HH)          // 512 row-pairs
#define EPSBN 1e-5f
#define BROFF 16777216ull   // per-branch offset for u/y1 (f16 els)

typedef _Float16 f16;
typedef _Float16 half8 __attribute__((ext_vector_type(8)));
typedef float f32x4 __attribute__((ext_vector_type(4)));

// ---------------------------------------------------------------------------
// K0: weight prep — rb_w fp32 [o][icg][3][3] -> f16 [g][mo][ks*32+ic]
// ---------------------------------------------------------------------------
__global__ __launch_bounds__(256) void k_wprep(
    const float* __restrict__ w1, const float* __restrict__ w2,
    f16* __restrict__ wp1, f16* __restrict__ wp2)
{
    int g = blockIdx.x; int which = blockIdx.y;
    const float* src = which ? w2 : w1;
    f16* dst = which ? wp2 : wp1;
    for (int p = threadIdx.x; p < 9216; p += 256) {
        int mo = p / 288; int kr = p - mo*288;
        int ks = kr >> 5; int ic = kr & 31;
        dst[g*9216 + p] = (f16)src[((g*32 + mo)*32 + ic)*9 + ks];
    }
}

// ---------------------------------------------------------------------------
// K1: fused 1x1 conv (64->64) + concat + batchnorm -> u (channel-last f16)
// MERGED: grid (512, 2) — blockIdx.y selects the branch (left/right).
// ---------------------------------------------------------------------------
__global__ __launch_bounds__(256) void k_catbn_m(
    const float* __restrict__ x_l, const float* __restrict__ x_r,
    const float* __restrict__ cw1, const float* __restrict__ cw2,
    const float* __restrict__ cb1, const float* __restrict__ cb2,
    const float* __restrict__ g, const float* __restrict__ bb_, const float* __restrict__ m,
    const float* __restrict__ v, f16* __restrict__ u)
{
    __shared__ f16 Xl[256][72];   // [px][ic]
    __shared__ f16 Wl[64][72];    // [oc][ic]
    __shared__ float sS[64], sT[64], sS2[64], sT2[64];
    int n = blockIdx.x; int br = blockIdx.y;
    int b = n >> 7; int h = n & 127; int t = threadIdx.x;
    const float* x  = br ? x_r : x_l;
    const float* cw = br ? cw2 : cw1;
    const float* cb = br ? cb2 : cb1;
    f16* ub = u + (size_t)br * BROFF;
    for (int p = t; p < 2048; p += 256) {
        int idx = p * 2; int o = idx >> 6, i = idx & 63;
        union { f16 h[2]; unsigned int u1; } pr;
        pr.h[0] = (f16)cw[idx]; pr.h[1] = (f16)cw[idx + 1];
        *(unsigned int*)&Wl[o][i] = pr.u1;
    }
    if (t < 64) {
        float inv = rsqrtf(v[t] + EPSBN); float s = g[t] * inv;
        sS[t] = s; sT[t] = bb_[t] + s * (cb[t] - m[t]);
        float inv2 = rsqrtf(v[t + 64] + EPSBN); float s2 = g[t + 64] * inv2;
        sS2[t] = s2; sT2[t] = bb_[t + 64] - s2 * m[t + 64];
    }
    __syncthreads();
    f16* up = ub + ((size_t)(n*256 + t)) * 128;
    for (int c8 = 0; c8 < 8; ++c8) {
        float xv8[8];
#pragma unroll
        for (int j = 0; j < 8; ++j)
            xv8[j] = x[(((b*64 + c8*8 + j)*128 + h) << 8) + t];
        union { f16 h[8]; uint4 v4; } pk;
#pragma unroll
        for (int j = 0; j < 8; ++j) {
            int c = c8*8 + j;
            pk.h[j] = (f16)(sS2[c]*xv8[j] + sT2[c]);
        }
        *(uint4*)(up + 64 + c8*8) = pk.v4;
#pragma unroll
        for (int j2 = 0; j2 < 4; ++j2) {
            union { f16 h[2]; unsigned int u1; } q;
            q.h[0] = (f16)xv8[j2*2]; q.h[1] = (f16)xv8[j2*2 + 1];
            *(unsigned int*)&Xl[t][c8*8 + j2*2] = q.u1;
        }
    }
    __syncthreads();
    int lane = t & 63, wv = t >> 6;
    int m16 = lane & 15, quad = lane >> 4;
    half8 af[4][2], bf[4][2];
#pragma unroll
    for (int mt = 0; mt < 4; ++mt)
#pragma unroll
        for (int kk = 0; kk < 2; ++kk)
            af[mt][kk] = *(const half8*)&Wl[mt*16 + m16][kk*32 + quad*8];
#pragma unroll
    for (int nt = 0; nt < 4; ++nt)
#pragma unroll
        for (int kk = 0; kk < 2; ++kk)
            bf[nt][kk] = *(const half8*)&Xl[wv*64 + nt*16 + m16][kk*32 + quad*8];
    f32x4 acc[4][4] = {};
#pragma unroll
    for (int mt = 0; mt < 4; ++mt)
#pragma unroll
        for (int nt = 0; nt < 4; ++nt) {
            acc[mt][nt] = __builtin_amdgcn_mfma_f32_16x16x32_f16(af[mt][0], bf[nt][0], acc[mt][nt], 0, 0, 0);
            acc[mt][nt] = __builtin_amdgcn_mfma_f32_16x16x32_f16(af[mt][1], bf[nt][1], acc[mt][nt], 0, 0, 0);
        }
#pragma unroll
    for (int mt = 0; mt < 4; ++mt) {
        int ocb = mt*16 + quad*4;
        float s4[4], t4[4];
        *(float4*)s4 = *(const float4*)&sS[ocb];
        *(float4*)t4 = *(const float4*)&sT[ocb];
#pragma unroll
        for (int nt = 0; nt < 4; ++nt) {
            int px = wv*64 + nt*16 + m16;
            union { f16 h[4]; uint2 u2; } ov;
#pragma unroll
            for (int r = 0; r < 4; ++r)
                ov.h[r] = (f16)(s4[r]*acc[mt][nt][r] + t4[r]);
            *(uint2*)(ub + ((size_t)(n*256 + px))*128 + ocb) = ov.u2;
        }
    }
}

// ---------------------------------------------------------------------------
// K2/K3: grouped 3x3 conv, implicit-GEMM f16 MFMA.
// R12: 512 threads (8 waves), 4 output rows per block (6 staged rows,
// 62.4 KB LDS) -> 2 blocks/CU = 16 waves/CU (+33% vs R11's 12), staging
// traffic 1.5 rows/output-row (-25%), grid 2048 = exactly 4 residency
// rounds.  Each wave: 16 px x 32 oc x 4 rows (same MFMA/output, half the
// ds_reads/wave).  Residual loads hoisted above the MFMA loop.
// grid (128 = b*htile32, 4 group, 4 = wtile + 2*branch).
// ---------------------------------------------------------------------------
template<bool LEAKY, bool RES>
__global__ __launch_bounds__(512, 2) void k_conv3r(
    const f16* __restrict__ inB, const f16* __restrict__ wp,
    const float* __restrict__ bias, f16* __restrict__ outB)
{
    __shared__ f16 Xl[6*130*40];  // [row][px][ic] px-stride 40
    int b = blockIdx.x >> 5; int h0 = (blockIdx.x & 31) * 4;
    int g = blockIdx.y;
    int wt = blockIdx.z & 1; int branch = blockIdx.z >> 1;
    int w0 = wt * 128;
    const f16* in = inB + (size_t)branch * BROFF;
    f16* out = outB + (size_t)branch * BROFF;
    int t = threadIdx.x;
    int lane = t & 63, wv = t >> 6;          // wv 0..7
    int m16 = lane & 15, quad = lane >> 4;
    const f16* wg = wp + g*9216;
    half8 af[2][9];
#pragma unroll
    for (int mt = 0; mt < 2; ++mt)
#pragma unroll
        for (int ks = 0; ks < 9; ++ks)
            af[mt][ks] = *(const half8*)(wg + (mt*16 + m16)*288 + ks*32 + quad*8);
    float bo[2][4];
#pragma unroll
    for (int mt = 0; mt < 2; ++mt)
#pragma unroll
        for (int r = 0; r < 4; ++r)
            bo[mt][r] = bias[g*32 + mt*16 + quad*4 + r];
    // ---- stage 6 input rows (h0-1 .. h0+4) ----
    for (int idx = t; idx < 3120; idx += 512) {
        int r = idx / 520; int rem = idx - r*520; int p = rem >> 2; int q = rem & 3;
        int hr = h0 + r - 1; int wg2 = w0 + p - 1;
        uint4 val = make_uint4(0,0,0,0);
        if ((unsigned)wg2 < 256u && (unsigned)hr < 128u)
            val = *(const uint4*)(in + ((size_t)((b*128 + hr)*256 + wg2))*128 + g*32 + q*8);
        *(uint4*)&Xl[(r*130 + p)*40 + q*8] = val;
    }
    __syncthreads();
    int pxl = wv*16 + m16;                   // 0..127 within the w-tile
    // ---- hoist residual loads (overlap HBM latency with MFMAs) ----
    uint2 resv[4][2];
    if (RES) {
#pragma unroll
        for (int rr = 0; rr < 4; ++rr)
#pragma unroll
            for (int mt = 0; mt < 2; ++mt) {
                size_t off = ((size_t)((b*128 + h0 + rr)*256 + w0 + pxl))*128
                           + g*32 + mt*16 + quad*4;
                resv[rr][mt] = *(const uint2*)(out + off);
            }
    }
#pragma unroll
    for (int rr = 0; rr < 4; ++rr) {
        f32x4 acc[2] = {};
#pragma unroll
        for (int ks = 0; ks < 9; ++ks) {
            int ky = ks / 3, kx = ks - ky*3;
            half8 bf0 = *(const half8*)&Xl[((rr + ky)*130 + pxl + kx)*40 + quad*8];
            acc[0] = __builtin_amdgcn_mfma_f32_16x16x32_f16(af[0][ks], bf0, acc[0], 0, 0, 0);
            acc[1] = __builtin_amdgcn_mfma_f32_16x16x32_f16(af[1][ks], bf0, acc[1], 0, 0, 0);
        }
        int h = h0 + rr;
#pragma unroll
        for (int mt = 0; mt < 2; ++mt) {
            int oc = g*32 + mt*16 + quad*4;
            size_t off = ((size_t)((b*128 + h)*256 + w0 + pxl))*128 + oc;
            float rv4[4] = {0.f, 0.f, 0.f, 0.f};
            if (RES) {
                union { f16 h[4]; uint2 v2; } rrd;
                rrd.v2 = resv[rr][mt];
#pragma unroll
                for (int r = 0; r < 4; ++r) rv4[r] = (float)rrd.h[r];
            }
            union { f16 h[4]; uint2 v2; } ov;
#pragma unroll
            for (int r = 0; r < 4; ++r) {
                float y = acc[mt][r] + bo[mt][r];
                if (LEAKY) y = y > 0.f ? y : 0.1f*y;
                if (RES) y += rv4[r];
                ov.h[r] = (f16)y;
            }
            *(uint2*)(out + off) = ov.v2;
        }
    }
}

// ---------------------------------------------------------------------------
// K4: grouped 1x1 conv (128->64, groups=2) + row-mean subtraction, MFMA f16.
// MERGED: grid (512, 2) — blockIdx.y selects branch (weights + output).
// ---------------------------------------------------------------------------
__global__ __launch_bounds__(256, 2) void k_conv1x1m(
    const f16* __restrict__ inB, const float* __restrict__ wq,
    const float* __restrict__ ws, f16* __restrict__ outq)
{
    __shared__ f16 Xl[256][72];       // one group's 64 ic (+8 pad)
    __shared__ f16 Wl[64][72];        // all 64 oc, within-group ic
    __shared__ float partial[4][64];  // per-wave px-sums per oc
    __shared__ float meanS[64];
    int n = blockIdx.x; int br = blockIdx.y; int t = threadIdx.x;
    const float* wgt = br ? ws : wq;
    const f16* in = inB + (size_t)br * BROFF;
    f16* outb = outq + (size_t)br * 8388608ull;
    int lane = t & 63, wv = t >> 6;
    int m16 = lane & 15, quad = lane >> 4;
    for (int p = t; p < 2048; p += 256) {
        int idx = p * 2; int o = idx >> 6, i = idx & 63;
        union { f16 h[2]; unsigned int u1; } pr;
        pr.h[0] = (f16)wgt[idx]; pr.h[1] = (f16)wgt[idx + 1];
        *(unsigned int*)&Wl[o][i] = pr.u1;
    }
    f32x4 acc[4][4] = {};             // [oc tile 0..3][px tile 0..3]
    const f16* rp = in + ((size_t)n*256 + t)*128;
    for (int g = 0; g < 2; ++g) {
#pragma unroll
        for (int i8 = 0; i8 < 8; ++i8)
            *(uint4*)&Xl[t][i8*8] = *(const uint4*)(rp + g*64 + i8*8);
        __syncthreads();
        half8 af[2][2], bf[4][2];
#pragma unroll
        for (int ml = 0; ml < 2; ++ml)
#pragma unroll
            for (int kk = 0; kk < 2; ++kk)
                af[ml][kk] = *(const half8*)&Wl[g*32 + ml*16 + m16][kk*32 + quad*8];
#pragma unroll
        for (int nt = 0; nt < 4; ++nt)
#pragma unroll
            for (int kk = 0; kk < 2; ++kk)
                bf[nt][kk] = *(const half8*)&Xl[wv*64 + nt*16 + m16][kk*32 + quad*8];
#pragma unroll
        for (int ml = 0; ml < 2; ++ml)
#pragma unroll
            for (int nt = 0; nt < 4; ++nt) {
                int mt = g*2 + ml;
                acc[mt][nt] = __builtin_amdgcn_mfma_f32_16x16x32_f16(af[ml][0], bf[nt][0], acc[mt][nt], 0, 0, 0);
                acc[mt][nt] = __builtin_amdgcn_mfma_f32_16x16x32_f16(af[ml][1], bf[nt][1], acc[mt][nt], 0, 0, 0);
            }
        __syncthreads();
    }
#pragma unroll
    for (int mt = 0; mt < 4; ++mt)
#pragma unroll
        for (int r = 0; r < 4; ++r) {
            float s = acc[mt][0][r] + acc[mt][1][r] + acc[mt][2][r] + acc[mt][3][r];
            s += __shfl_xor(s, 1); s += __shfl_xor(s, 2);
            s += __shfl_xor(s, 4); s += __shfl_xor(s, 8);
            if (m16 == 0) partial[wv][mt*16 + quad*4 + r] = s;
        }
    __syncthreads();
    if (t < 64)
        meanS[t] = (partial[0][t] + partial[1][t] + partial[2][t] + partial[3][t]) * (1.0f/256.0f);
    __syncthreads();
    f16* qp = outb + ((size_t)n*256)*64;
#pragma unroll
    for (int mt = 0; mt < 4; ++mt) {
        int ocb = mt*16 + quad*4;
        float m4[4]; *(float4*)m4 = *(const float4*)&meanS[ocb];
#pragma unroll
        for (int nt = 0; nt < 4; ++nt) {
            int px = wv*64 + nt*16 + m16;
            union { f16 h[4]; uint2 u2; } ov;
#pragma unroll
            for (int r = 0; r < 4; ++r)
                ov.h[r] = (f16)(acc[mt][nt][r] - m4[r]);
            *(uint2*)(qp + (size_t)px*64 + ocb) = ov.u2;
        }
    }
}

// ---------------------------------------------------------------------------
// K5: fused bidirectional attention (attn5, unchanged).
// LDS: Pl 20.8K + Sr 20.5K + Xl 5K + stats 4K = 50.5 KiB -> 3 blocks/CU.
// ---------------------------------------------------------------------------
__device__ __forceinline__ void attn_pass5(
    const f16* __restrict__ Ap, const f16* __restrict__ Bp, char* pool,
    const float* __restrict__ myM, const float* __restrict__ myI,  // by row
    const float* __restrict__ oM,  const float* __restrict__ oI,   // by col
    const float* __restrict__ xB, const float* __restrict__ xP,
    float* __restrict__ outp, int b, int h, int t)
{
    f16 (*Pl)[40] = (f16(*)[40])pool;                 // P, rows +2 (pad)
    f16 (*Sr)[40] = (f16(*)[40])(pool + 20800);       // raw S, rows 0..255
    f16 (*Xl)[40] = (f16(*)[40])(pool + 41280);
    float* scr = (float*)(pool + 41280);              // overlays Xl post-loop
    float* Vv  = (float*)(pool + 43328);
    int lane = t & 63, wv = t >> 6;
    int m16 = lane & 15, quad = lane >> 4;
    int W = wv * 32;
    int r = t & 255, hc = t >> 8;
    int cbase = hc * 16;
    int xc = t >> 3, xj = (t & 7) * 4;
    const float* xg = xB + ((size_t)(b*64 + xc)*128 + h)*256;
    half8 af[2][2];
#pragma unroll
    for (int mt = 0; mt < 2; ++mt)
#pragma unroll
        for (int kk = 0; kk < 2; ++kk)
            af[mt][kk] = *(const half8*)(Ap + (size_t)(W + mt*16 + m16)*64 + kk*32 + quad*8);
    float rmv[8], riv[8];
#pragma unroll
    for (int mt = 0; mt < 2; ++mt)
#pragma unroll
        for (int rr = 0; rr < 4; ++rr) {
            int row = W + mt*16 + quad*4 + rr;
            rmv[mt*4 + rr] = myM[row];
            riv[mt*4 + rr] = myI[row];
        }
    f32x4 acc[2][4] = {};
    float vacc = 0.f;
    for (int kc = 0; kc < 256; kc += 32) {
        half8 bf[2][2];
#pragma unroll
        for (int nt = 0; nt < 2; ++nt)
#pragma unroll
            for (int kk = 0; kk < 2; ++kk)
                bf[nt][kk] = *(const half8*)(Bp + (size_t)(kc + nt*16 + m16)*64 + kk*32 + quad*8);
        f32x4 s1[2][2] = {};
#pragma unroll
        for (int mt = 0; mt < 2; ++mt)
#pragma unroll
            for (int nt = 0; nt < 2; ++nt) {
                s1[mt][nt] = __builtin_amdgcn_mfma_f32_16x16x32_f16(af[mt][0], bf[nt][0], s1[mt][nt], 0, 0, 0);
                s1[mt][nt] = __builtin_amdgcn_mfma_f32_16x16x32_f16(af[mt][1], bf[nt][1], s1[mt][nt], 0, 0, 0);
            }
        {
            float4 x4 = *(const float4*)(xg + kc + xj);
            union { f16 h[4]; uint2 v2; } px;
            px.h[0] = (f16)x4.x; px.h[1] = (f16)x4.y;
            px.h[2] = (f16)x4.z; px.h[3] = (f16)x4.w;
            *(uint2*)&Xl[xc][xj] = px.v2;
        }
#pragma unroll
        for (int mt = 0; mt < 2; ++mt)
#pragma unroll
            for (int nt = 0; nt < 2; ++nt)
#pragma unroll
                for (int rr = 0; rr < 4; ++rr) {
                    int row = W + mt*16 + quad*4 + rr;
                    int col = nt*16 + m16;
                    f16 hv = (f16)s1[mt][nt][rr];
                    Sr[row][col] = hv;
                    int ridx = mt*4 + rr;
                    Pl[row + 2][col] = (f16)(__expf((float)hv - rmv[ridx]) * riv[ridx]);
                }
        __syncthreads();
#pragma unroll
        for (int j8 = 0; j8 < 2; ++j8) {
            const char* wb = (const char*)&Pl[r][cbase + j8*8];
            half8 w0 = *(const half8*)(wb);
            half8 w1 = *(const half8*)(wb + 80);
            half8 w2 = *(const half8*)(wb + 160);
            half8 w3 = *(const half8*)(wb + 240);
            half8 w4 = *(const half8*)(wb + 320);
            half8 win = w0 + w1 + w2 + w3 + w4;
            half8 rw = *(const half8*)&Sr[r][cbase + j8*8];
#pragma unroll
            for (int e = 0; e < 8; ++e) {
                int j = kc + cbase + j8*8 + e;
                float Bv = __expf((float)rw[e] - oM[j]) * oI[j];
                vacc = fmaf((float)win[e], Bv, vacc);
            }
        }
        half8 pa[2], xb_[4];
#pragma unroll
        for (int mt = 0; mt < 2; ++mt)
            pa[mt] = *(const half8*)((const char*)&Pl[W + mt*16 + m16 + 2][0] + quad*16);
#pragma unroll
        for (int nt = 0; nt < 4; ++nt)
            xb_[nt] = *(const half8*)((const char*)&Xl[nt*16 + m16][0] + quad*16);
#pragma unroll
        for (int mt = 0; mt < 2; ++mt)
#pragma unroll
            for (int nt = 0; nt < 4; ++nt)
                acc[mt][nt] = __builtin_amdgcn_mfma_f32_16x16x32_f16(pa[mt], xb_[nt], acc[mt][nt], 0, 0, 0);
        __syncthreads();
    }
    scr[hc*256 + r] = vacc;
    __syncthreads();
    if (t < 256) Vv[t] = scr[t] + scr[256 + t];
    __syncthreads();
#pragma unroll
    for (int mt = 0; mt < 2; ++mt) {
        int i0 = W + mt*16 + quad*4;
        float v4[4];
        *(float4*)v4 = *(const float4*)&Vv[i0];
        float tv[4];
#pragma unroll
        for (int rr = 0; rr < 4; ++rr) tv[rr] = tanhf(5.f*v4[rr]);
#pragma unroll
        for (int nt = 0; nt < 4; ++nt) {
            int c = nt*16 + m16;
            size_t base = (((size_t)(b*64 + c)*128 + h) << 8) + i0;
            float xp4[4]; *(float4*)xp4 = *(const float4*)&xP[base];
            float o4[4];
#pragma unroll
            for (int rr = 0; rr < 4; ++rr)
                o4[rr] = xp4[rr]*(1.f - tv[rr]) + acc[mt][nt][rr]*tv[rr];
            *(float4*)&outp[base] = *(float4*)o4;
        }
    }
}

__global__ __launch_bounds__(512, 4) void k_attn5(
    const f16* __restrict__ Q, const f16* __restrict__ K,
    const float* __restrict__ xl, const float* __restrict__ xr,
    float* __restrict__ outL, float* __restrict__ outR)
{
    __shared__ __align__(16) char pool[46400];  // Pl/Sr/Xl ∪ colM/colS ∪ scr/Vv
    __shared__ float rmS[256], riS[256], cmS[256], ciS[256];
    float* colM = (float*)pool;            // [8][256] per-wave col partial max
    float* colS = (float*)(pool + 8192);   // [8][256] per-wave col partial sum
    int n = blockIdx.x; int b = n >> 7; int h = n & 127;
    int t = threadIdx.x;
    int lane = t & 63, wv = t >> 6;
    int m16 = lane & 15, quad = lane >> 4;
    int W = wv * 32;

    // ---- phase 1: S = Q·K^T, stats only (no store) ----
    const f16* ag = Q + (size_t)n*16384;
    const f16* bg = K + (size_t)n*16384;
    half8 af1[2][2];
#pragma unroll
    for (int mt = 0; mt < 2; ++mt)
#pragma unroll
        for (int kk = 0; kk < 2; ++kk)
            af1[mt][kk] = *(const half8*)(ag + (size_t)(W + mt*16 + m16)*64 + kk*32 + quad*8);
    float rowm[8], rows_[8];
#pragma unroll
    for (int i = 0; i < 8; ++i) { rowm[i] = -1e30f; rows_[i] = 0.f; }
    for (int jc = 0; jc < 256; jc += 64) {
        half8 bf1[4][2];
#pragma unroll
        for (int nt = 0; nt < 4; ++nt)
#pragma unroll
            for (int kk = 0; kk < 2; ++kk)
                bf1[nt][kk] = *(const half8*)(bg + (size_t)(jc + nt*16 + m16)*64 + kk*32 + quad*8);
        f32x4 acc1[2][4] = {};
#pragma unroll
        for (int mt = 0; mt < 2; ++mt)
#pragma unroll
            for (int nt = 0; nt < 4; ++nt) {
                acc1[mt][nt] = __builtin_amdgcn_mfma_f32_16x16x32_f16(af1[mt][0], bf1[nt][0], acc1[mt][nt], 0, 0, 0);
                acc1[mt][nt] = __builtin_amdgcn_mfma_f32_16x16x32_f16(af1[mt][1], bf1[nt][1], acc1[mt][nt], 0, 0, 0);
            }
#pragma unroll
        for (int mt = 0; mt < 2; ++mt)
#pragma unroll
            for (int nt = 0; nt < 4; ++nt)
#pragma unroll
                for (int r = 0; r < 4; ++r)
                    acc1[mt][nt][r] = (float)(f16)acc1[mt][nt][r];
        // row stats: per-thread ONLINE over in-lane 4 cols (no shfl here)
#pragma unroll
        for (int mt = 0; mt < 2; ++mt)
#pragma unroll
            for (int r = 0; r < 4; ++r) {
                int idx = mt*4 + r;
                float v0 = acc1[mt][0][r], v1 = acc1[mt][1][r];
                float v2 = acc1[mt][2][r], v3 = acc1[mt][3][r];
                float lm = fmaxf(fmaxf(v0, v1), fmaxf(v2, v3));
                float nm = fmaxf(rowm[idx], lm);
                rows_[idx] = rows_[idx]*__expf(rowm[idx] - nm)
                           + __expf(v0 - nm) + __expf(v1 - nm)
                           + __expf(v2 - nm) + __expf(v3 - nm);
                rowm[idx] = nm;
            }
        // col stats: reduce over 8 in-lane rows + 4 quads -> per-wave partial
#pragma unroll
        for (int nt = 0; nt < 4; ++nt) {
            float lm = acc1[0][nt][0];
#pragma unroll
            for (int r = 1; r < 4; ++r) lm = fmaxf(lm, acc1[0][nt][r]);
#pragma unroll
            for (int r = 0; r < 4; ++r) lm = fmaxf(lm, acc1[1][nt][r]);
            lm = fmaxf(lm, __shfl_xor(lm, 16));
            lm = fmaxf(lm, __shfl_xor(lm, 32));
            float le = 0.f;
#pragma unroll
            for (int mt2 = 0; mt2 < 2; ++mt2)
#pragma unroll
                for (int r = 0; r < 4; ++r) le += __expf(acc1[mt2][nt][r] - lm);
            le += __shfl_xor(le, 16); le += __shfl_xor(le, 32);
            if (quad == 0) {
                int col = jc + nt*16 + m16;
                colM[wv*256 + col] = lm;
                colS[wv*256 + col] = le;
            }
        }
    }
    // row stats: single 4-step merge across the 16 m16-lanes
#pragma unroll
    for (int idx = 0; idx < 8; ++idx) {
        float m = rowm[idx], s = rows_[idx];
#pragma unroll
        for (int off = 1; off < 16; off <<= 1) {
            float m2 = __shfl_xor(m, off);
            float s2 = __shfl_xor(s, off);
            float nm = fmaxf(m, m2);
            s = s*__expf(m - nm) + s2*__expf(m2 - nm);
            m = nm;
        }
        rowm[idx] = m; rows_[idx] = s;
    }
    if (m16 == 0) {
#pragma unroll
        for (int mt = 0; mt < 2; ++mt)
#pragma unroll
            for (int r = 0; r < 4; ++r) {
                int row = W + mt*16 + quad*4 + r;
                rmS[row] = rowm[mt*4 + r];
                riS[row] = 1.0f / rows_[mt*4 + r];
            }
    }
    __syncthreads();
    if (t < 256) {
        float m = colM[t], s = colS[t];
#pragma unroll
        for (int w = 1; w < 8; ++w) {
            float m2 = colM[w*256 + t], s2 = colS[w*256 + t];
            float nm = fmaxf(m, m2);
            s = s*__expf(m - nm) + s2*__expf(m2 - nm);
            m = nm;
        }
        cmS[t] = m; ciS[t] = 1.0f / s;
    }
    __syncthreads();
    if (t < 10)       *(uint4*)(pool + t*16)              = make_uint4(0,0,0,0);
    else if (t < 20)  *(uint4*)(pool + 20640 + (t-10)*16) = make_uint4(0,0,0,0);

    attn_pass5(ag, bg, pool, rmS, riS, cmS, ciS, xr, xl, outL, b, h, t);
    __syncthreads();
    attn_pass5(bg, ag, pool, cmS, ciS, rmS, riS, xl, xr, outR, b, h, t);
}

// ---------------------------------------------------------------------------
extern "C" void kernel_launch(void* const* d_in, const int* in_sizes, int n_in,
                              void* d_out, int out_size, void* d_ws, size_t ws_size,
                              hipStream_t stream)
{
    const float* x_left  = (const float*)d_in[0];
    const float* x_right = (const float*)d_in[1];
    const float* conv1_w = (const float*)d_in[2];
    const float* conv1_b = (const float*)d_in[3];
    const float* conv2_w = (const float*)d_in[4];
    const float* conv2_b = (const float*)d_in[5];
    const float* bn_g    = (const float*)d_in[6];
    const float* bn_b    = (const float*)d_in[7];
    const float* bn_m    = (const float*)d_in[8];
    const float* bn_v    = (const float*)d_in[9];
    const float* rb_w1   = (const float*)d_in[10];
    const float* rb_b1   = (const float*)d_in[11];
    const float* rb_w2   = (const float*)d_in[12];
    const float* rb_b2   = (const float*)d_in[13];
    const float* bq_w    = (const float*)d_in[14];
    const float* bs_w    = (const float*)d_in[16];

    // Workspace layout (f16 els) — max 83,959,808 < 85.0M known-good (R0):
    //   u   [2 branches] : 0        .. 33,554,432   (becomes r in-place)
    //   y1  [2 branches] : 33,554,432 .. 67,108,864
    //   Qh               : 67,108,864 (8,388,608);  Kh = Qh + 8,388,608
    //   Wp1/Wp2          : 83,886,080 .. +73,728
    f16* W16 = (f16*)d_ws;
    f16* u   = W16;
    f16* y1  = W16 + 33554432;
    f16* Qh  = W16 + 67108864;
    f16* Kh  = W16 + 75497472;
    f16* Wp1 = W16 + 83886080;
    f16* Wp2 = W16 + 83886080 + 36864;

    float* out_left  = (float*)d_out;
    float* out_right = (float*)d_out + 8388608;

    // ---- weight prep ----
    k_wprep<<<dim3(4, 2), 256, 0, stream>>>(rb_w1, rb_w2, Wp1, Wp2);

    // ---- both branches, merged dispatches ----
    k_catbn_m<<<dim3(NN, 2), 256, 0, stream>>>(
        x_left, x_right, conv1_w, conv2_w, conv1_b, conv2_b,
        bn_g, bn_b, bn_m, bn_v, u);
    k_conv3r<true,  false><<<dim3(128, 4, 4), 512, 0, stream>>>(u,  Wp1, rb_b1, y1);
    k_conv3r<false, true ><<<dim3(128, 4, 4), 512, 0, stream>>>(y1, Wp2, rb_b2, u);  // r -> u in-place
    k_conv1x1m<<<dim3(NN, 2), 256, 0, stream>>>(u, bq_w, bs_w, Qh);

    // ---- fused attention tail ----
    k_attn5<<<NN, 512, 0, stream>>>(Qh, Kh, x_left, x_right, out_left, out_right);
}